// Round 2
// baseline (648.113 us; speedup 1.0000x reference)
//
#include <hip/hip_runtime.h>
#include <math.h>

typedef __attribute__((ext_vector_type(8))) short short8;
typedef __attribute__((ext_vector_type(4))) float f32x4;

#define DEV __device__ __forceinline__

static constexpr int B_ = 4, C_ = 256, S_ = 2048, H_ = 8, O3_ = 768;
static constexpr int TOPK = 512;
static constexpr int QT = 16;          // q rows per workgroup in attention
static constexpr int SCS = 2052;       // score row stride (floats), %32==4 -> 2-way LDS aliasing (free)
static constexpr int LDS_SC = QT * SCS;
static constexpr int LDS_RED = 8 * 16 * 33;
static constexpr size_t K3_LDS_BYTES = (size_t)(LDS_SC + LDS_RED) * 4;  // 148224 B

DEV unsigned short f2bf(float f) {
  unsigned u = __float_as_uint(f);
  return (unsigned short)((u + 0x7FFFu + ((u >> 16) & 1u)) >> 16);  // RNE
}
DEV float bf2f(unsigned short h) { return __uint_as_float(((unsigned)h) << 16); }
DEV float key_inv(unsigned k) {
  unsigned u = (k & 0x80000000u) ? (k ^ 0x80000000u) : ~k;
  return __uint_as_float(u);
}

// ---------------- K0a: weights -> bf16 hi/lo (qkv), bf16 (proj) ----------------
__global__ void k_convw(const float* __restrict__ wqkv, const float* __restrict__ wproj,
                        unsigned short* __restrict__ wq_hi, unsigned short* __restrict__ wq_lo,
                        unsigned short* __restrict__ wproj_bf) {
  int i = blockIdx.x * 256 + threadIdx.x;
  if (i < O3_ * C_) {
    float f = wqkv[i];
    unsigned short h = f2bf(f);
    wq_hi[i] = h;
    wq_lo[i] = f2bf(f - bf2f(h));
  }
  if (i < C_ * C_) wproj_bf[i] = f2bf(wproj[i]);
}

// ---------------- K0b: transpose x [b][c][s] -> xT hi/lo bf16 [b][s][c] ----------------
__global__ void k_xt(const float* __restrict__ x, unsigned short* __restrict__ xT_hi,
                     unsigned short* __restrict__ xT_lo) {
  __shared__ float t[32][33];
  int b = blockIdx.z;
  int c0 = blockIdx.y * 32, s0 = blockIdx.x * 32;
  int tx = threadIdx.x, ty = threadIdx.y;
  const float* xb = x + (size_t)b * C_ * S_;
#pragma unroll
  for (int j = 0; j < 4; ++j)
    t[ty + 8 * j][tx] = xb[(size_t)(c0 + ty + 8 * j) * S_ + s0 + tx];
  __syncthreads();
  unsigned short* hb = xT_hi + (size_t)b * S_ * C_;
  unsigned short* lb = xT_lo + (size_t)b * S_ * C_;
#pragma unroll
  for (int j = 0; j < 4; ++j) {
    float f = t[tx][ty + 8 * j];
    unsigned short h = f2bf(f);
    size_t o = (size_t)(s0 + ty + 8 * j) * C_ + c0 + tx;
    hb[o] = h;
    lb[o] = f2bf(f - bf2f(h));
  }
}

// ---------------- K1: qkv_raw = W_qkv @ x  (split-bf16 3-pass MFMA, ~fp32 accurate) ----------------
__global__ __launch_bounds__(256) void k_qkv(const unsigned short* __restrict__ w_hi,
                                             const unsigned short* __restrict__ w_lo,
                                             const unsigned short* __restrict__ x_hi,
                                             const unsigned short* __restrict__ x_lo,
                                             float* __restrict__ raw) {
  int b = blockIdx.z;
  int m0 = blockIdx.y * 64, n0 = blockIdx.x * 64;
  int tid = threadIdx.x, lane = tid & 63, wid = tid >> 6;
  int l15 = lane & 15, lh = lane >> 4;
  int wm = (wid >> 1) * 32, wn = (wid & 1) * 32;
  const unsigned short* xhb = x_hi + (size_t)b * S_ * C_;
  const unsigned short* xlb = x_lo + (size_t)b * S_ * C_;
  f32x4 acc[2][2] = {};
  int mA = m0 + wm + l15;
  int nB = n0 + wn + l15;
  for (int k0 = 0; k0 < C_; k0 += 32) {
    int kk = k0 + lh * 8;
    short8 a0h = *(const short8*)(w_hi + (size_t)mA * C_ + kk);
    short8 a1h = *(const short8*)(w_hi + (size_t)(mA + 16) * C_ + kk);
    short8 a0l = *(const short8*)(w_lo + (size_t)mA * C_ + kk);
    short8 a1l = *(const short8*)(w_lo + (size_t)(mA + 16) * C_ + kk);
    short8 b0h = *(const short8*)(xhb + (size_t)nB * C_ + kk);
    short8 b1h = *(const short8*)(xhb + (size_t)(nB + 16) * C_ + kk);
    short8 b0l = *(const short8*)(xlb + (size_t)nB * C_ + kk);
    short8 b1l = *(const short8*)(xlb + (size_t)(nB + 16) * C_ + kk);
    acc[0][0] = __builtin_amdgcn_mfma_f32_16x16x32_bf16(a0h, b0h, acc[0][0], 0, 0, 0);
    acc[0][1] = __builtin_amdgcn_mfma_f32_16x16x32_bf16(a0h, b1h, acc[0][1], 0, 0, 0);
    acc[1][0] = __builtin_amdgcn_mfma_f32_16x16x32_bf16(a1h, b0h, acc[1][0], 0, 0, 0);
    acc[1][1] = __builtin_amdgcn_mfma_f32_16x16x32_bf16(a1h, b1h, acc[1][1], 0, 0, 0);
    acc[0][0] = __builtin_amdgcn_mfma_f32_16x16x32_bf16(a0h, b0l, acc[0][0], 0, 0, 0);
    acc[0][1] = __builtin_amdgcn_mfma_f32_16x16x32_bf16(a0h, b1l, acc[0][1], 0, 0, 0);
    acc[1][0] = __builtin_amdgcn_mfma_f32_16x16x32_bf16(a1h, b0l, acc[1][0], 0, 0, 0);
    acc[1][1] = __builtin_amdgcn_mfma_f32_16x16x32_bf16(a1h, b1l, acc[1][1], 0, 0, 0);
    acc[0][0] = __builtin_amdgcn_mfma_f32_16x16x32_bf16(a0l, b0h, acc[0][0], 0, 0, 0);
    acc[0][1] = __builtin_amdgcn_mfma_f32_16x16x32_bf16(a0l, b1h, acc[0][1], 0, 0, 0);
    acc[1][0] = __builtin_amdgcn_mfma_f32_16x16x32_bf16(a1l, b0h, acc[1][0], 0, 0, 0);
    acc[1][1] = __builtin_amdgcn_mfma_f32_16x16x32_bf16(a1l, b1h, acc[1][1], 0, 0, 0);
  }
  float* rawb = raw + (size_t)b * O3_ * S_;
#pragma unroll
  for (int i = 0; i < 2; ++i)
#pragma unroll
    for (int j = 0; j < 2; ++j)
#pragma unroll
      for (int r = 0; r < 4; ++r) {
        int row = m0 + wm + i * 16 + lh * 4 + r;
        int col = n0 + wn + j * 16 + l15;
        rawb[(size_t)row * S_ + col] = acc[i][j][r];
      }
}

// ---------------- K2: depthwise conv + head split + l2norm (+temperature fold) ----------------
DEV float conv3(const float* __restrict__ rp, const float* __restrict__ w, int s) {
  float a = (s > 0) ? rp[s - 1] : 0.f;
  float b = rp[s];
  float c = (s < S_ - 1) ? rp[s + 1] : 0.f;
  return w[0] * a + w[1] * b + w[2] * c;
}

__global__ __launch_bounds__(256) void k_dwnorm(const float* __restrict__ raw,
                                                const float* __restrict__ wdw,
                                                const float* __restrict__ temp,
                                                unsigned short* __restrict__ q_hi,
                                                unsigned short* __restrict__ q_lo,
                                                unsigned short* __restrict__ k_hi,
                                                unsigned short* __restrict__ k_lo,
                                                unsigned short* __restrict__ vt) {
  int b = blockIdx.z, h = blockIdx.y;
  int s = blockIdx.x * 256 + threadIdx.x;
  const float* rawb = raw + (size_t)b * O3_ * S_;
  float tph = temp[h];
  float qv[32], kv[32];
  float sq = 0.f, sk = 0.f;
  size_t bh = (size_t)(b * H_ + h);
#pragma unroll
  for (int d = 0; d < 32; ++d) {
    int oq = h * 32 + d;
    float q = conv3(rawb + (size_t)oq * S_, wdw + oq * 3, s);
    qv[d] = q; sq += q * q;
    int ok = oq + 256;
    float k = conv3(rawb + (size_t)ok * S_, wdw + ok * 3, s);
    kv[d] = k; sk += k * k;
    int ov = oq + 512;
    float v = conv3(rawb + (size_t)ov * S_, wdw + ov * 3, s);
    vt[(bh * 32 + d) * S_ + s] = f2bf(v);
  }
  float iq = tph / fmaxf(sqrtf(sq), 1e-12f);
  float ik = 1.f / fmaxf(sqrtf(sk), 1e-12f);
  size_t base = (bh * S_ + s) * 32;
#pragma unroll
  for (int d = 0; d < 32; ++d) {
    float qf = qv[d] * iq;
    unsigned short qh = f2bf(qf);
    q_hi[base + d] = qh;
    q_lo[base + d] = f2bf(qf - bf2f(qh));
    float kf = kv[d] * ik;
    unsigned short kh = f2bf(kf);
    k_hi[base + d] = kh;
    k_lo[base + d] = f2bf(kf - bf2f(kh));
  }
}

// ---------------- K3: fused QK^T (split-bf16) -> exact top-512 -> softmax -> PV ----------------
__global__ __launch_bounds__(512) void k_attn(const unsigned short* __restrict__ q_hi,
                                              const unsigned short* __restrict__ q_lo,
                                              const unsigned short* __restrict__ k_hi,
                                              const unsigned short* __restrict__ k_lo,
                                              const unsigned short* __restrict__ vt,
                                              unsigned short* __restrict__ ao) {
  extern __shared__ float smem[];
  float* sc = smem;              // [QT][SCS]
  float* red = smem + LDS_SC;    // [8][16][33]
  int bid = blockIdx.x;
  int tile = bid & 127;          // S/QT
  int bh = bid >> 7;
  int q0 = tile * QT;
  int tid = threadIdx.x, lane = tid & 63, wid = tid >> 6;
  int l15 = lane & 15, lh = lane >> 4;
  const unsigned short* vb = vt + (size_t)bh * 32 * S_;
  size_t qoff = ((size_t)bh * S_ + q0 + l15) * 32 + lh * 8;

  // Phase 1: scores tile [16][2048] = Q(16x32) @ K^T(32x2048), split-bf16 3-pass
  short8 ah = *(const short8*)(q_hi + qoff);
  short8 al = *(const short8*)(q_lo + qoff);
  int tbase = wid * 256;
  for (int nt = 0; nt < 16; ++nt) {
    int t0 = tbase + nt * 16;
    size_t koff = ((size_t)bh * S_ + t0 + l15) * 32 + lh * 8;
    short8 bh_ = *(const short8*)(k_hi + koff);
    short8 bl_ = *(const short8*)(k_lo + koff);
    f32x4 d = {};
    d = __builtin_amdgcn_mfma_f32_16x16x32_bf16(ah, bh_, d, 0, 0, 0);
    d = __builtin_amdgcn_mfma_f32_16x16x32_bf16(ah, bl_, d, 0, 0, 0);
    d = __builtin_amdgcn_mfma_f32_16x16x32_bf16(al, bh_, d, 0, 0, 0);
#pragma unroll
    for (int r = 0; r < 4; ++r)
      sc[(lh * 4 + r) * SCS + t0 + l15] = d[r];
  }
  __syncthreads();

  // Phase 2: per-row exact top-512 threshold + softmax (wave w owns rows 2w, 2w+1)
  for (int rr = wid * 2; rr < wid * 2 + 2; ++rr) {
    unsigned key[32];
#pragma unroll
    for (int j = 0; j < 32; ++j) {
      unsigned u = __float_as_uint(sc[rr * SCS + lane + 64 * j]);
      key[j] = (u & 0x80000000u) ? ~u : (u | 0x80000000u);
    }
    unsigned lo = 0, hi = 0xFFFFFFFFu, Tkey = 0;
    int cntGT = 0;
    bool exact = false;
    while (lo < hi) {
      unsigned mid = lo + ((hi - lo) >> 1);
      int c = 0;
#pragma unroll
      for (int j = 0; j < 32; ++j) c += (key[j] > mid) ? 1 : 0;
#pragma unroll
      for (int m = 1; m < 64; m <<= 1) c += __shfl_xor(c, m);
      if (c == TOPK) { Tkey = mid; cntGT = c; exact = true; break; }
      if (c > TOPK) lo = mid + 1; else hi = mid;
    }
    if (!exact) {
      Tkey = lo;
      int c = 0;
#pragma unroll
      for (int j = 0; j < 32; ++j) c += (key[j] > Tkey) ? 1 : 0;
#pragma unroll
      for (int m = 1; m < 64; m <<= 1) c += __shfl_xor(c, m);
      cntGT = c;
    }
    int need = TOPK - cntGT;
    unsigned selbits = 0;
    if (need > 0) {
      // ties broken by lowest t index (jax top_k order); col = lane + 64*j
      int base = 0;
      unsigned long long lmask = (lane == 0) ? 0ull : (~0ull >> (64 - lane));
#pragma unroll
      for (int j = 0; j < 32; ++j) {
        bool tie = (key[j] == Tkey);
        unsigned long long m = __ballot(tie);
        int rank = base + (int)__popcll(m & lmask);
        if (key[j] > Tkey || (tie && rank < need)) selbits |= (1u << j);
        base += (int)__popcll(m);
      }
    } else {
#pragma unroll
      for (int j = 0; j < 32; ++j)
        if (key[j] > Tkey) selbits |= (1u << j);
    }
    unsigned mk = 0;
#pragma unroll
    for (int j = 0; j < 32; ++j) mk = (key[j] > mk) ? key[j] : mk;
#pragma unroll
    for (int m = 1; m < 64; m <<= 1) { unsigned o = __shfl_xor(mk, m); mk = (o > mk) ? o : mk; }
    float mv = fminf(fmaxf(key_inv(mk), -10000.f), 10000.f);
    float ssum = 0.f;
#pragma unroll
    for (int j = 0; j < 32; ++j) {
      float f = fminf(fmaxf(key_inv(key[j]), -10000.f), 10000.f);
      float e = ((selbits >> j) & 1u) ? __expf(f - mv) : 0.f;
      key[j] = __float_as_uint(e);
      ssum += e;
    }
#pragma unroll
    for (int m = 1; m < 64; m <<= 1) ssum += __shfl_xor(ssum, m);
    float is = 1.f / ssum;
#pragma unroll
    for (int j = 0; j < 32; ++j)
      sc[rr * SCS + lane + 64 * j] = __uint_as_float(key[j]) * is;
  }
  __syncthreads();

  // Phase 3: PV — out(16x32) = P(16x2048) @ V(2048x32); wave w covers t in [256w, 256w+256)
  f32x4 acc0 = {}, acc1 = {};
  for (int kt = 0; kt < 8; ++kt) {
    int t0 = wid * 256 + kt * 32 + lh * 8;
    const f32x4* prow = (const f32x4*)&sc[l15 * SCS + t0];
    f32x4 p0 = prow[0], p1 = prow[1];
    short8 af;
#pragma unroll
    for (int i = 0; i < 4; ++i) af[i] = (short)f2bf(p0[i]);
#pragma unroll
    for (int i = 0; i < 4; ++i) af[4 + i] = (short)f2bf(p1[i]);
    short8 b0 = *(const short8*)(vb + (size_t)l15 * S_ + t0);
    short8 b1 = *(const short8*)(vb + (size_t)(16 + l15) * S_ + t0);
    acc0 = __builtin_amdgcn_mfma_f32_16x16x32_bf16(af, b0, acc0, 0, 0, 0);
    acc1 = __builtin_amdgcn_mfma_f32_16x16x32_bf16(af, b1, acc1, 0, 0, 0);
  }
#pragma unroll
  for (int r = 0; r < 4; ++r) {
    red[(wid * 16 + lh * 4 + r) * 33 + l15] = acc0[r];
    red[(wid * 16 + lh * 4 + r) * 33 + 16 + l15] = acc1[r];
  }
  __syncthreads();
  int row = tid >> 5, d = tid & 31;
  float s = 0.f;
#pragma unroll
  for (int w = 0; w < 8; ++w) s += red[(w * 16 + row) * 33 + d];
  ao[((size_t)bh * S_ + q0 + row) * 32 + d] = f2bf(s);
}

// ---------------- K4: output projection ----------------
__global__ __launch_bounds__(256) void k_proj(const unsigned short* __restrict__ wbf,
                                              const unsigned short* __restrict__ ao,
                                              float* __restrict__ out) {
  int b = blockIdx.z;
  int m0 = blockIdx.y * 64, n0 = blockIdx.x * 64;
  int tid = threadIdx.x, lane = tid & 63, wid = tid >> 6;
  int l15 = lane & 15, lh = lane >> 4;
  int wm = (wid >> 1) * 32, wn = (wid & 1) * 32;
  const unsigned short* aob = ao + (size_t)b * H_ * S_ * 32;
  f32x4 acc[2][2] = {};
  int mA = m0 + wm + l15;
  int nB = n0 + wn + l15;
  for (int k0 = 0; k0 < C_; k0 += 32) {
    int kk = k0 + lh * 8;
    int hh = kk >> 5;
    int dd = kk & 31;
    short8 a0 = *(const short8*)(wbf + (size_t)mA * C_ + kk);
    short8 a1 = *(const short8*)(wbf + (size_t)(mA + 16) * C_ + kk);
    short8 b0 = *(const short8*)(aob + ((size_t)hh * S_ + nB) * 32 + dd);
    short8 b1 = *(const short8*)(aob + ((size_t)hh * S_ + nB + 16) * 32 + dd);
    acc[0][0] = __builtin_amdgcn_mfma_f32_16x16x32_bf16(a0, b0, acc[0][0], 0, 0, 0);
    acc[0][1] = __builtin_amdgcn_mfma_f32_16x16x32_bf16(a0, b1, acc[0][1], 0, 0, 0);
    acc[1][0] = __builtin_amdgcn_mfma_f32_16x16x32_bf16(a1, b0, acc[1][0], 0, 0, 0);
    acc[1][1] = __builtin_amdgcn_mfma_f32_16x16x32_bf16(a1, b1, acc[1][1], 0, 0, 0);
  }
  float* ob = out + (size_t)b * C_ * S_;
#pragma unroll
  for (int i = 0; i < 2; ++i)
#pragma unroll
    for (int j = 0; j < 2; ++j)
#pragma unroll
      for (int r = 0; r < 4; ++r) {
        int row = m0 + wm + i * 16 + lh * 4 + r;
        int col = n0 + wn + j * 16 + l15;
        ob[(size_t)row * S_ + col] = acc[i][j][r];
      }
}

extern "C" void kernel_launch(void* const* d_in, const int* in_sizes, int n_in,
                              void* d_out, int out_size, void* d_ws, size_t ws_size,
                              hipStream_t stream) {
  const float* x = (const float*)d_in[0];
  const float* wqkv = (const float*)d_in[1];
  const float* wdw = (const float*)d_in[2];
  const float* wproj = (const float*)d_in[3];
  const float* temp = (const float*)d_in[4];
  float* out = (float*)d_out;

  char* ws = (char*)d_ws;
  size_t off = 0;
  auto alloc = [&](size_t bytes) -> void* {
    void* p = ws + off;
    off += (bytes + 255) & ~(size_t)255;
    return p;
  };
  // x_hi/x_lo are dead after k_qkv -> reused as q_hi/q_lo (same size: B*S*C == B*H*S*32).
  unsigned short* x_hi     = (unsigned short*)alloc((size_t)B_ * S_ * C_ * 2);
  unsigned short* x_lo     = (unsigned short*)alloc((size_t)B_ * S_ * C_ * 2);
  unsigned short* wq_hi    = (unsigned short*)alloc((size_t)O3_ * C_ * 2);
  unsigned short* wq_lo    = (unsigned short*)alloc((size_t)O3_ * C_ * 2);
  unsigned short* wproj_bf = (unsigned short*)alloc((size_t)C_ * C_ * 2);
  float*          raw      = (float*)alloc((size_t)B_ * O3_ * S_ * 4);
  unsigned short* k_hi     = (unsigned short*)alloc((size_t)B_ * H_ * S_ * 32 * 2);
  unsigned short* k_lo     = (unsigned short*)alloc((size_t)B_ * H_ * S_ * 32 * 2);
  unsigned short* vt       = (unsigned short*)alloc((size_t)B_ * H_ * 32 * S_ * 2);
  unsigned short* q_hi     = x_hi;                 // alias (x dead after k_qkv)
  unsigned short* q_lo     = x_lo;                 // alias
  unsigned short* ao       = (unsigned short*)raw; // alias (raw dead after k_dwnorm)

  (void)hipFuncSetAttribute(reinterpret_cast<const void*>(k_attn),
                            hipFuncAttributeMaxDynamicSharedMemorySize, (int)K3_LDS_BYTES);

  k_convw<<<dim3((O3_ * C_ + 255) / 256), dim3(256), 0, stream>>>(wqkv, wproj, wq_hi, wq_lo, wproj_bf);
  k_xt<<<dim3(S_ / 32, C_ / 32, B_), dim3(32, 8), 0, stream>>>(x, x_hi, x_lo);
  k_qkv<<<dim3(S_ / 64, O3_ / 64, B_), dim3(256), 0, stream>>>(wq_hi, wq_lo, x_hi, x_lo, raw);
  k_dwnorm<<<dim3(S_ / 256, H_, B_), dim3(256), 0, stream>>>(raw, wdw, temp, q_hi, q_lo, k_hi, k_lo, vt);
  k_attn<<<dim3(B_ * H_ * (S_ / QT)), dim3(512), K3_LDS_BYTES, stream>>>(q_hi, q_lo, k_hi, k_lo, vt, ao);
  k_proj<<<dim3(S_ / 64, C_ / 64, B_), dim3(256), 0, stream>>>(wproj_bf, ao, out);
}

// Round 3
// 476.871 us; speedup vs baseline: 1.3591x; 1.3591x over previous
//
#include <hip/hip_runtime.h>
#include <math.h>

typedef __attribute__((ext_vector_type(8))) short short8;
typedef __attribute__((ext_vector_type(4))) float f32x4;

#define DEV __device__ __forceinline__

static constexpr int B_ = 4, C_ = 256, S_ = 2048, H_ = 8, O3_ = 768;
static constexpr int TOPK = 512;
static constexpr int QT = 8;           // q rows per workgroup in attention
static constexpr int SCS = 2052;       // fp32 score row stride (floats); %32==4
static constexpr int PST = 2056;       // bf16 P row stride (elems); 2056*2=4112 B, 16B-aligned
static constexpr int LDS_SC_FLOATS = QT * SCS;     // 16416 floats = 65664 B (P bf16 aliases: 8*2056*2=32896 B)
static constexpr int LDS_RED_FLOATS = 8 * 8 * 33;  // 2112 floats = 8448 B
static constexpr size_t K3_LDS_BYTES = (size_t)(LDS_SC_FLOATS + LDS_RED_FLOATS) * 4;  // 74112 B -> 2 WGs/CU

DEV unsigned short f2bf(float f) {
  unsigned u = __float_as_uint(f);
  return (unsigned short)((u + 0x7FFFu + ((u >> 16) & 1u)) >> 16);  // RNE
}
DEV float bf2f(unsigned short h) { return __uint_as_float(((unsigned)h) << 16); }

// ---------------- K0a: weights -> bf16 hi/lo (qkv), bf16 (proj) ----------------
__global__ void k_convw(const float* __restrict__ wqkv, const float* __restrict__ wproj,
                        unsigned short* __restrict__ wq_hi, unsigned short* __restrict__ wq_lo,
                        unsigned short* __restrict__ wproj_bf) {
  int i = blockIdx.x * 256 + threadIdx.x;
  if (i < O3_ * C_) {
    float f = wqkv[i];
    unsigned short h = f2bf(f);
    wq_hi[i] = h;
    wq_lo[i] = f2bf(f - bf2f(h));
  }
  if (i < C_ * C_) wproj_bf[i] = f2bf(wproj[i]);
}

// ---------------- K0b: transpose x [b][c][s] -> xT hi/lo bf16 [b][s][c] ----------------
__global__ void k_xt(const float* __restrict__ x, unsigned short* __restrict__ xT_hi,
                     unsigned short* __restrict__ xT_lo) {
  __shared__ float t[32][33];
  int b = blockIdx.z;
  int c0 = blockIdx.y * 32, s0 = blockIdx.x * 32;
  int tx = threadIdx.x, ty = threadIdx.y;
  const float* xb = x + (size_t)b * C_ * S_;
#pragma unroll
  for (int j = 0; j < 4; ++j)
    t[ty + 8 * j][tx] = xb[(size_t)(c0 + ty + 8 * j) * S_ + s0 + tx];
  __syncthreads();
  unsigned short* hb = xT_hi + (size_t)b * S_ * C_;
  unsigned short* lb = xT_lo + (size_t)b * S_ * C_;
#pragma unroll
  for (int j = 0; j < 4; ++j) {
    float f = t[tx][ty + 8 * j];
    unsigned short h = f2bf(f);
    size_t o = (size_t)(s0 + ty + 8 * j) * C_ + c0 + tx;
    hb[o] = h;
    lb[o] = f2bf(f - bf2f(h));
  }
}

// ---------------- K1: qkv_raw = W_qkv @ x  (split-bf16 3-pass MFMA, ~fp32 accurate) ----------------
__global__ __launch_bounds__(256) void k_qkv(const unsigned short* __restrict__ w_hi,
                                             const unsigned short* __restrict__ w_lo,
                                             const unsigned short* __restrict__ x_hi,
                                             const unsigned short* __restrict__ x_lo,
                                             float* __restrict__ raw) {
  int b = blockIdx.z;
  int m0 = blockIdx.y * 64, n0 = blockIdx.x * 64;
  int tid = threadIdx.x, lane = tid & 63, wid = tid >> 6;
  int l15 = lane & 15, lh = lane >> 4;
  int wm = (wid >> 1) * 32, wn = (wid & 1) * 32;
  const unsigned short* xhb = x_hi + (size_t)b * S_ * C_;
  const unsigned short* xlb = x_lo + (size_t)b * S_ * C_;
  f32x4 acc[2][2] = {};
  int mA = m0 + wm + l15;
  int nB = n0 + wn + l15;
  for (int k0 = 0; k0 < C_; k0 += 32) {
    int kk = k0 + lh * 8;
    short8 a0h = *(const short8*)(w_hi + (size_t)mA * C_ + kk);
    short8 a1h = *(const short8*)(w_hi + (size_t)(mA + 16) * C_ + kk);
    short8 a0l = *(const short8*)(w_lo + (size_t)mA * C_ + kk);
    short8 a1l = *(const short8*)(w_lo + (size_t)(mA + 16) * C_ + kk);
    short8 b0h = *(const short8*)(xhb + (size_t)nB * C_ + kk);
    short8 b1h = *(const short8*)(xhb + (size_t)(nB + 16) * C_ + kk);
    short8 b0l = *(const short8*)(xlb + (size_t)nB * C_ + kk);
    short8 b1l = *(const short8*)(xlb + (size_t)(nB + 16) * C_ + kk);
    acc[0][0] = __builtin_amdgcn_mfma_f32_16x16x32_bf16(a0h, b0h, acc[0][0], 0, 0, 0);
    acc[0][1] = __builtin_amdgcn_mfma_f32_16x16x32_bf16(a0h, b1h, acc[0][1], 0, 0, 0);
    acc[1][0] = __builtin_amdgcn_mfma_f32_16x16x32_bf16(a1h, b0h, acc[1][0], 0, 0, 0);
    acc[1][1] = __builtin_amdgcn_mfma_f32_16x16x32_bf16(a1h, b1h, acc[1][1], 0, 0, 0);
    acc[0][0] = __builtin_amdgcn_mfma_f32_16x16x32_bf16(a0h, b0l, acc[0][0], 0, 0, 0);
    acc[0][1] = __builtin_amdgcn_mfma_f32_16x16x32_bf16(a0h, b1l, acc[0][1], 0, 0, 0);
    acc[1][0] = __builtin_amdgcn_mfma_f32_16x16x32_bf16(a1h, b0l, acc[1][0], 0, 0, 0);
    acc[1][1] = __builtin_amdgcn_mfma_f32_16x16x32_bf16(a1h, b1l, acc[1][1], 0, 0, 0);
    acc[0][0] = __builtin_amdgcn_mfma_f32_16x16x32_bf16(a0l, b0h, acc[0][0], 0, 0, 0);
    acc[0][1] = __builtin_amdgcn_mfma_f32_16x16x32_bf16(a0l, b1h, acc[0][1], 0, 0, 0);
    acc[1][0] = __builtin_amdgcn_mfma_f32_16x16x32_bf16(a1l, b0h, acc[1][0], 0, 0, 0);
    acc[1][1] = __builtin_amdgcn_mfma_f32_16x16x32_bf16(a1l, b1h, acc[1][1], 0, 0, 0);
  }
  float* rawb = raw + (size_t)b * O3_ * S_;
#pragma unroll
  for (int i = 0; i < 2; ++i)
#pragma unroll
    for (int j = 0; j < 2; ++j)
#pragma unroll
      for (int r = 0; r < 4; ++r) {
        int row = m0 + wm + i * 16 + lh * 4 + r;
        int col = n0 + wn + j * 16 + l15;
        rawb[(size_t)row * S_ + col] = acc[i][j][r];
      }
}

// ---------------- K2: depthwise conv + head split + l2norm (+temperature fold) ----------------
DEV float conv3(const float* __restrict__ rp, const float* __restrict__ w, int s) {
  float a = (s > 0) ? rp[s - 1] : 0.f;
  float b = rp[s];
  float c = (s < S_ - 1) ? rp[s + 1] : 0.f;
  return w[0] * a + w[1] * b + w[2] * c;
}

__global__ __launch_bounds__(256) void k_dwnorm(const float* __restrict__ raw,
                                                const float* __restrict__ wdw,
                                                const float* __restrict__ temp,
                                                unsigned short* __restrict__ q_hi,
                                                unsigned short* __restrict__ q_lo,
                                                unsigned short* __restrict__ k_hi,
                                                unsigned short* __restrict__ k_lo,
                                                unsigned short* __restrict__ vt) {
  int b = blockIdx.z, h = blockIdx.y;
  int s = blockIdx.x * 256 + threadIdx.x;
  const float* rawb = raw + (size_t)b * O3_ * S_;
  float tph = temp[h];
  float qv[32], kv[32];
  float sq = 0.f, sk = 0.f;
  size_t bh = (size_t)(b * H_ + h);
#pragma unroll
  for (int d = 0; d < 32; ++d) {
    int oq = h * 32 + d;
    float q = conv3(rawb + (size_t)oq * S_, wdw + oq * 3, s);
    qv[d] = q; sq += q * q;
    int ok = oq + 256;
    float k = conv3(rawb + (size_t)ok * S_, wdw + ok * 3, s);
    kv[d] = k; sk += k * k;
    int ov = oq + 512;
    float v = conv3(rawb + (size_t)ov * S_, wdw + ov * 3, s);
    vt[(bh * 32 + d) * S_ + s] = f2bf(v);
  }
  float iq = tph / fmaxf(sqrtf(sq), 1e-12f);
  float ik = 1.f / fmaxf(sqrtf(sk), 1e-12f);
  size_t base = (bh * S_ + s) * 32;
#pragma unroll
  for (int d = 0; d < 32; ++d) {
    float qf = qv[d] * iq;
    unsigned short qh = f2bf(qf);
    q_hi[base + d] = qh;
    q_lo[base + d] = f2bf(qf - bf2f(qh));
    float kf = kv[d] * ik;
    unsigned short kh = f2bf(kf);
    k_hi[base + d] = kh;
    k_lo[base + d] = f2bf(kf - bf2f(kh));
  }
}

// ---------------- K3: fused QK^T (split-bf16) -> exact top-512 -> softmax -> PV ----------------
// 8 waves, QT=8 rows; wave w owns score row w. 2 WGs/CU (74 KB LDS).
__global__ __launch_bounds__(512, 4) void k_attn(const unsigned short* __restrict__ q_hi,
                                                 const unsigned short* __restrict__ q_lo,
                                                 const unsigned short* __restrict__ k_hi,
                                                 const unsigned short* __restrict__ k_lo,
                                                 const unsigned short* __restrict__ vt,
                                                 unsigned short* __restrict__ ao) {
  extern __shared__ float smem[];
  float* sc = smem;                               // [QT][SCS] fp32 scores
  unsigned short* P = (unsigned short*)smem;      // [QT][PST] bf16 probs (aliases sc)
  float* red = smem + LDS_SC_FLOATS;              // [8][8][33]
  int bid = blockIdx.x;
  int tile = bid & 255;                           // S/QT tiles per (b,h)
  int bh = bid >> 8;
  int q0 = tile * QT;
  int tid = threadIdx.x, lane = tid & 63, wid = tid >> 6;
  int l15 = lane & 15, lh = lane >> 4;
  const unsigned short* vb = vt + (size_t)bh * 32 * S_;

  // ---- Phase 1: scores [8][2048] = Q(8x32) @ K^T ; Q rows duplicated into 16-row A-frag ----
  size_t qoff = ((size_t)bh * S_ + q0 + (l15 & 7)) * 32 + lh * 8;
  short8 ah = *(const short8*)(q_hi + qoff);
  short8 al = *(const short8*)(q_lo + qoff);
  size_t kbase = (size_t)bh * S_ * 32;
  int cw = wid * 256;  // this wave's 256-col span
  short8 khf = *(const short8*)(k_hi + kbase + (size_t)(cw + l15) * 32 + lh * 8);
  short8 klf = *(const short8*)(k_lo + kbase + (size_t)(cw + l15) * 32 + lh * 8);
  for (int nt = 0; nt < 16; ++nt) {
    short8 khn = khf, kln = klf;
    if (nt < 15) {
      size_t ko = kbase + (size_t)(cw + (nt + 1) * 16 + l15) * 32 + lh * 8;
      khn = *(const short8*)(k_hi + ko);
      kln = *(const short8*)(k_lo + ko);
    }
    f32x4 d = {};
    d = __builtin_amdgcn_mfma_f32_16x16x32_bf16(ah, khf, d, 0, 0, 0);
    d = __builtin_amdgcn_mfma_f32_16x16x32_bf16(ah, klf, d, 0, 0, 0);
    d = __builtin_amdgcn_mfma_f32_16x16x32_bf16(al, khf, d, 0, 0, 0);
    if (lh < 2) {  // rows 0..7 valid (8..15 are duplicates)
      int t0 = cw + nt * 16;
#pragma unroll
      for (int r = 0; r < 4; ++r)
        sc[(lh * 4 + r) * SCS + t0 + l15] = d[r];
    }
    khf = khn; klf = kln;
  }
  __syncthreads();

  // ---- Phase 2: per-row exact top-512 (value-space bisection, ballot counts) + softmax ----
  {
    int rr = wid;  // row
    float v[32];
#pragma unroll
    for (int j = 0; j < 32; ++j) v[j] = sc[rr * SCS + lane + 64 * j];
    __syncthreads();  // everyone done reading sc; safe to overwrite with P (aliased)

    float vmax = v[0], vmin = v[0];
#pragma unroll
    for (int j = 1; j < 32; ++j) { vmax = fmaxf(vmax, v[j]); vmin = fminf(vmin, v[j]); }
#pragma unroll
    for (int m = 1; m < 64; m <<= 1) {
      vmax = fmaxf(vmax, __shfl_xor(vmax, m));
      vmin = fminf(vmin, __shfl_xor(vmin, m));
    }

    float vlo = vmin - 1e-3f, vhi = vmax;
    float T = vhi;
    int cntGT = 0, chi = 0;
    bool exact = false;
    for (int it = 0; it < 64; ++it) {
      float piv = 0.5f * (vlo + vhi);
      if (!(piv > vlo && piv < vhi)) break;  // interval collapsed (ties at threshold)
      int c = 0;
#pragma unroll
      for (int j = 0; j < 32; ++j)
        c += (int)__popcll(__ballot(v[j] > piv));
      if (c == TOPK) { T = piv; cntGT = c; exact = true; break; }
      if (c > TOPK) vlo = piv;
      else { vhi = piv; chi = c; }
    }
    if (!exact) { T = vhi; cntGT = chi; }

    unsigned selbits = 0;
#pragma unroll
    for (int j = 0; j < 32; ++j)
      if (v[j] > T) selbits |= (1u << j);
    int need = TOPK - cntGT;
    if (need > 0) {
      // ties broken by lowest column index (jax top_k order); col = lane + 64*j (j-major)
      int base = 0;
      unsigned long long lmask = (lane == 0) ? 0ull : (~0ull >> (64 - lane));
#pragma unroll
      for (int j = 0; j < 32; ++j) {
        bool tie = (v[j] == T);
        unsigned long long m = __ballot(tie);
        int rank = base + (int)__popcll(m & lmask);
        if (tie && rank < need) selbits |= (1u << j);
        base += (int)__popcll(m);
      }
    }

    float ssum = 0.f;
#pragma unroll
    for (int j = 0; j < 32; ++j) {
      float e = ((selbits >> j) & 1u) ? __expf(v[j] - vmax) : 0.f;
      v[j] = e;
      ssum += e;
    }
#pragma unroll
    for (int m = 1; m < 64; m <<= 1) ssum += __shfl_xor(ssum, m);
    float is = 1.f / ssum;
#pragma unroll
    for (int j = 0; j < 32; ++j)
      P[rr * PST + lane + 64 * j] = f2bf(v[j] * is);
  }
  __syncthreads();

  // ---- Phase 3: PV — out(8x32) = P(8x2048) @ V(2048x32); wave w covers t in [256w,256w+256) ----
  {
    int prow = (l15 & 7) * PST;
    short8 a0 = *(const short8*)(P + prow + cw + lh * 8);
    short8 b0 = *(const short8*)(vb + (size_t)l15 * S_ + cw + lh * 8);
    short8 b1 = *(const short8*)(vb + (size_t)(16 + l15) * S_ + cw + lh * 8);
    f32x4 acc0 = {}, acc1 = {};
    for (int kt = 0; kt < 8; ++kt) {
      short8 an = a0, b0n = b0, b1n = b1;
      if (kt < 7) {
        int t1 = cw + (kt + 1) * 32 + lh * 8;
        an = *(const short8*)(P + prow + t1);
        b0n = *(const short8*)(vb + (size_t)l15 * S_ + t1);
        b1n = *(const short8*)(vb + (size_t)(16 + l15) * S_ + t1);
      }
      acc0 = __builtin_amdgcn_mfma_f32_16x16x32_bf16(a0, b0, acc0, 0, 0, 0);
      acc1 = __builtin_amdgcn_mfma_f32_16x16x32_bf16(a0, b1, acc1, 0, 0, 0);
      a0 = an; b0 = b0n; b1 = b1n;
    }
    if (lh < 2) {  // out rows 0..7 valid
#pragma unroll
      for (int r = 0; r < 4; ++r) {
        red[(wid * 8 + lh * 4 + r) * 33 + l15] = acc0[r];
        red[(wid * 8 + lh * 4 + r) * 33 + 16 + l15] = acc1[r];
      }
    }
  }
  __syncthreads();
  if (tid < 256) {
    int row = tid >> 5, d = tid & 31;
    float s = 0.f;
#pragma unroll
    for (int w = 0; w < 8; ++w) s += red[(w * 8 + row) * 33 + d];
    ao[((size_t)bh * S_ + q0 + row) * 32 + d] = f2bf(s);
  }
}

// ---------------- K4: output projection ----------------
__global__ __launch_bounds__(256) void k_proj(const unsigned short* __restrict__ wbf,
                                              const unsigned short* __restrict__ ao,
                                              float* __restrict__ out) {
  int b = blockIdx.z;
  int m0 = blockIdx.y * 64, n0 = blockIdx.x * 64;
  int tid = threadIdx.x, lane = tid & 63, wid = tid >> 6;
  int l15 = lane & 15, lh = lane >> 4;
  int wm = (wid >> 1) * 32, wn = (wid & 1) * 32;
  const unsigned short* aob = ao + (size_t)b * H_ * S_ * 32;
  f32x4 acc[2][2] = {};
  int mA = m0 + wm + l15;
  int nB = n0 + wn + l15;
  for (int k0 = 0; k0 < C_; k0 += 32) {
    int kk = k0 + lh * 8;
    int hh = kk >> 5;
    int dd = kk & 31;
    short8 a0 = *(const short8*)(wbf + (size_t)mA * C_ + kk);
    short8 a1 = *(const short8*)(wbf + (size_t)(mA + 16) * C_ + kk);
    short8 b0 = *(const short8*)(aob + ((size_t)hh * S_ + nB) * 32 + dd);
    short8 b1 = *(const short8*)(aob + ((size_t)hh * S_ + nB + 16) * 32 + dd);
    acc[0][0] = __builtin_amdgcn_mfma_f32_16x16x32_bf16(a0, b0, acc[0][0], 0, 0, 0);
    acc[0][1] = __builtin_amdgcn_mfma_f32_16x16x32_bf16(a0, b1, acc[0][1], 0, 0, 0);
    acc[1][0] = __builtin_amdgcn_mfma_f32_16x16x32_bf16(a1, b0, acc[1][0], 0, 0, 0);
    acc[1][1] = __builtin_amdgcn_mfma_f32_16x16x32_bf16(a1, b1, acc[1][1], 0, 0, 0);
  }
  float* ob = out + (size_t)b * C_ * S_;
#pragma unroll
  for (int i = 0; i < 2; ++i)
#pragma unroll
    for (int j = 0; j < 2; ++j)
#pragma unroll
      for (int r = 0; r < 4; ++r) {
        int row = m0 + wm + i * 16 + lh * 4 + r;
        int col = n0 + wn + j * 16 + l15;
        ob[(size_t)row * S_ + col] = acc[i][j][r];
      }
}

extern "C" void kernel_launch(void* const* d_in, const int* in_sizes, int n_in,
                              void* d_out, int out_size, void* d_ws, size_t ws_size,
                              hipStream_t stream) {
  const float* x = (const float*)d_in[0];
  const float* wqkv = (const float*)d_in[1];
  const float* wdw = (const float*)d_in[2];
  const float* wproj = (const float*)d_in[3];
  const float* temp = (const float*)d_in[4];
  float* out = (float*)d_out;

  char* ws = (char*)d_ws;
  size_t off = 0;
  auto alloc = [&](size_t bytes) -> void* {
    void* p = ws + off;
    off += (bytes + 255) & ~(size_t)255;
    return p;
  };
  unsigned short* x_hi     = (unsigned short*)alloc((size_t)B_ * S_ * C_ * 2);
  unsigned short* x_lo     = (unsigned short*)alloc((size_t)B_ * S_ * C_ * 2);
  unsigned short* wq_hi    = (unsigned short*)alloc((size_t)O3_ * C_ * 2);
  unsigned short* wq_lo    = (unsigned short*)alloc((size_t)O3_ * C_ * 2);
  unsigned short* wproj_bf = (unsigned short*)alloc((size_t)C_ * C_ * 2);
  float*          raw      = (float*)alloc((size_t)B_ * O3_ * S_ * 4);
  unsigned short* k_hi     = (unsigned short*)alloc((size_t)B_ * H_ * S_ * 32 * 2);
  unsigned short* k_lo     = (unsigned short*)alloc((size_t)B_ * H_ * S_ * 32 * 2);
  unsigned short* vt       = (unsigned short*)alloc((size_t)B_ * H_ * 32 * S_ * 2);
  unsigned short* q_hi     = x_hi;                 // alias (x dead after k_qkv)
  unsigned short* q_lo     = x_lo;                 // alias
  unsigned short* ao       = (unsigned short*)raw; // alias (raw dead after k_dwnorm)

  (void)hipFuncSetAttribute(reinterpret_cast<const void*>(k_attn),
                            hipFuncAttributeMaxDynamicSharedMemorySize, (int)K3_LDS_BYTES);

  k_convw<<<dim3((O3_ * C_ + 255) / 256), dim3(256), 0, stream>>>(wqkv, wproj, wq_hi, wq_lo, wproj_bf);
  k_xt<<<dim3(S_ / 32, C_ / 32, B_), dim3(32, 8), 0, stream>>>(x, x_hi, x_lo);
  k_qkv<<<dim3(S_ / 64, O3_ / 64, B_), dim3(256), 0, stream>>>(wq_hi, wq_lo, x_hi, x_lo, raw);
  k_dwnorm<<<dim3(S_ / 256, H_, B_), dim3(256), 0, stream>>>(raw, wdw, temp, q_hi, q_lo, k_hi, k_lo, vt);
  k_attn<<<dim3(B_ * H_ * (S_ / QT)), dim3(512), K3_LDS_BYTES, stream>>>(q_hi, q_lo, k_hi, k_lo, vt, ao);
  k_proj<<<dim3(S_ / 64, C_ / 64, B_), dim3(256), 0, stream>>>(wproj_bf, ao, out);
}

// Round 4
// 383.842 us; speedup vs baseline: 1.6885x; 1.2424x over previous
//
#include <hip/hip_runtime.h>
#include <math.h>

typedef __attribute__((ext_vector_type(8))) short short8;
typedef __attribute__((ext_vector_type(4))) float f32x4;

#define DEV __device__ __forceinline__

static constexpr int B_ = 4, C_ = 256, S_ = 2048, H_ = 8, O3_ = 768;
static constexpr int TOPK = 512;
static constexpr int QT = 8;            // q rows per workgroup in attention
static constexpr int HCOLS = 1024;      // score cols staged per pass
static constexpr int HSTR = 1028;       // fp32 score row stride (half buffer); 4*HSTR%128==16 ->写入两半错开16银行
static constexpr int PST = 2056;        // bf16 P row stride; 2056*2=4112 B (16B aligned)
// LDS: one region, 8*1028*4 = 32896 B. P (8*2056*2=32896 B) aliases it exactly.
// red (8*8*33*4 = 8448 B) aliases P after a barrier. -> 4 WGs/CU.
static constexpr size_t K3_LDS_BYTES = (size_t)QT * HSTR * 4;  // 32896 B

DEV unsigned short f2bf(float f) {
  unsigned u = __float_as_uint(f);
  return (unsigned short)((u + 0x7FFFu + ((u >> 16) & 1u)) >> 16);  // RNE
}
DEV float bf2f(unsigned short h) { return __uint_as_float(((unsigned)h) << 16); }

// ---------------- K0a: weights -> bf16 hi/lo (qkv), bf16 (proj) ----------------
__global__ void k_convw(const float* __restrict__ wqkv, const float* __restrict__ wproj,
                        unsigned short* __restrict__ wq_hi, unsigned short* __restrict__ wq_lo,
                        unsigned short* __restrict__ wproj_bf) {
  int i = blockIdx.x * 256 + threadIdx.x;
  if (i < O3_ * C_) {
    float f = wqkv[i];
    unsigned short h = f2bf(f);
    wq_hi[i] = h;
    wq_lo[i] = f2bf(f - bf2f(h));
  }
  if (i < C_ * C_) wproj_bf[i] = f2bf(wproj[i]);
}

// ---------------- K0b: transpose x [b][c][s] -> xT hi/lo bf16 [b][s][c] ----------------
__global__ void k_xt(const float* __restrict__ x, unsigned short* __restrict__ xT_hi,
                     unsigned short* __restrict__ xT_lo) {
  __shared__ float t[32][33];
  int b = blockIdx.z;
  int c0 = blockIdx.y * 32, s0 = blockIdx.x * 32;
  int tx = threadIdx.x, ty = threadIdx.y;
  const float* xb = x + (size_t)b * C_ * S_;
#pragma unroll
  for (int j = 0; j < 4; ++j)
    t[ty + 8 * j][tx] = xb[(size_t)(c0 + ty + 8 * j) * S_ + s0 + tx];
  __syncthreads();
  unsigned short* hb = xT_hi + (size_t)b * S_ * C_;
  unsigned short* lb = xT_lo + (size_t)b * S_ * C_;
#pragma unroll
  for (int j = 0; j < 4; ++j) {
    float f = t[tx][ty + 8 * j];
    unsigned short h = f2bf(f);
    size_t o = (size_t)(s0 + ty + 8 * j) * C_ + c0 + tx;
    hb[o] = h;
    lb[o] = f2bf(f - bf2f(h));
  }
}

// ---------------- K1: qkv_raw = W_qkv @ x  (split-bf16 3-pass MFMA, ~fp32 accurate) ----------------
__global__ __launch_bounds__(256) void k_qkv(const unsigned short* __restrict__ w_hi,
                                             const unsigned short* __restrict__ w_lo,
                                             const unsigned short* __restrict__ x_hi,
                                             const unsigned short* __restrict__ x_lo,
                                             float* __restrict__ raw) {
  int b = blockIdx.z;
  int m0 = blockIdx.y * 64, n0 = blockIdx.x * 64;
  int tid = threadIdx.x, lane = tid & 63, wid = tid >> 6;
  int l15 = lane & 15, lh = lane >> 4;
  int wm = (wid >> 1) * 32, wn = (wid & 1) * 32;
  const unsigned short* xhb = x_hi + (size_t)b * S_ * C_;
  const unsigned short* xlb = x_lo + (size_t)b * S_ * C_;
  f32x4 acc[2][2] = {};
  int mA = m0 + wm + l15;
  int nB = n0 + wn + l15;
  for (int k0 = 0; k0 < C_; k0 += 32) {
    int kk = k0 + lh * 8;
    short8 a0h = *(const short8*)(w_hi + (size_t)mA * C_ + kk);
    short8 a1h = *(const short8*)(w_hi + (size_t)(mA + 16) * C_ + kk);
    short8 a0l = *(const short8*)(w_lo + (size_t)mA * C_ + kk);
    short8 a1l = *(const short8*)(w_lo + (size_t)(mA + 16) * C_ + kk);
    short8 b0h = *(const short8*)(xhb + (size_t)nB * C_ + kk);
    short8 b1h = *(const short8*)(xhb + (size_t)(nB + 16) * C_ + kk);
    short8 b0l = *(const short8*)(xlb + (size_t)nB * C_ + kk);
    short8 b1l = *(const short8*)(xlb + (size_t)(nB + 16) * C_ + kk);
    acc[0][0] = __builtin_amdgcn_mfma_f32_16x16x32_bf16(a0h, b0h, acc[0][0], 0, 0, 0);
    acc[0][1] = __builtin_amdgcn_mfma_f32_16x16x32_bf16(a0h, b1h, acc[0][1], 0, 0, 0);
    acc[1][0] = __builtin_amdgcn_mfma_f32_16x16x32_bf16(a1h, b0h, acc[1][0], 0, 0, 0);
    acc[1][1] = __builtin_amdgcn_mfma_f32_16x16x32_bf16(a1h, b1h, acc[1][1], 0, 0, 0);
    acc[0][0] = __builtin_amdgcn_mfma_f32_16x16x32_bf16(a0h, b0l, acc[0][0], 0, 0, 0);
    acc[0][1] = __builtin_amdgcn_mfma_f32_16x16x32_bf16(a0h, b1l, acc[0][1], 0, 0, 0);
    acc[1][0] = __builtin_amdgcn_mfma_f32_16x16x32_bf16(a1h, b0l, acc[1][0], 0, 0, 0);
    acc[1][1] = __builtin_amdgcn_mfma_f32_16x16x32_bf16(a1h, b1l, acc[1][1], 0, 0, 0);
    acc[0][0] = __builtin_amdgcn_mfma_f32_16x16x32_bf16(a0l, b0h, acc[0][0], 0, 0, 0);
    acc[0][1] = __builtin_amdgcn_mfma_f32_16x16x32_bf16(a0l, b1h, acc[0][1], 0, 0, 0);
    acc[1][0] = __builtin_amdgcn_mfma_f32_16x16x32_bf16(a1l, b0h, acc[1][0], 0, 0, 0);
    acc[1][1] = __builtin_amdgcn_mfma_f32_16x16x32_bf16(a1l, b1h, acc[1][1], 0, 0, 0);
  }
  float* rawb = raw + (size_t)b * O3_ * S_;
#pragma unroll
  for (int i = 0; i < 2; ++i)
#pragma unroll
    for (int j = 0; j < 2; ++j)
#pragma unroll
      for (int r = 0; r < 4; ++r) {
        int row = m0 + wm + i * 16 + lh * 4 + r;
        int col = n0 + wn + j * 16 + l15;
        rawb[(size_t)row * S_ + col] = acc[i][j][r];
      }
}

// ---------------- K2: depthwise conv + head split + l2norm (+temperature fold) ----------------
DEV float conv3(const float* __restrict__ rp, const float* __restrict__ w, int s) {
  float a = (s > 0) ? rp[s - 1] : 0.f;
  float b = rp[s];
  float c = (s < S_ - 1) ? rp[s + 1] : 0.f;
  return w[0] * a + w[1] * b + w[2] * c;
}

__global__ __launch_bounds__(256) void k_dwnorm(const float* __restrict__ raw,
                                                const float* __restrict__ wdw,
                                                const float* __restrict__ temp,
                                                unsigned short* __restrict__ q_hi,
                                                unsigned short* __restrict__ q_lo,
                                                unsigned short* __restrict__ k_hi,
                                                unsigned short* __restrict__ k_lo,
                                                unsigned short* __restrict__ vt) {
  int b = blockIdx.z, h = blockIdx.y;
  int s = blockIdx.x * 256 + threadIdx.x;
  const float* rawb = raw + (size_t)b * O3_ * S_;
  float tph = temp[h];
  float qv[32], kv[32];
  float sq = 0.f, sk = 0.f;
  size_t bh = (size_t)(b * H_ + h);
#pragma unroll
  for (int d = 0; d < 32; ++d) {
    int oq = h * 32 + d;
    float q = conv3(rawb + (size_t)oq * S_, wdw + oq * 3, s);
    qv[d] = q; sq += q * q;
    int ok = oq + 256;
    float k = conv3(rawb + (size_t)ok * S_, wdw + ok * 3, s);
    kv[d] = k; sk += k * k;
    int ov = oq + 512;
    float v = conv3(rawb + (size_t)ov * S_, wdw + ov * 3, s);
    vt[(bh * 32 + d) * S_ + s] = f2bf(v);
  }
  float iq = tph / fmaxf(sqrtf(sq), 1e-12f);
  float ik = 1.f / fmaxf(sqrtf(sk), 1e-12f);
  size_t base = (bh * S_ + s) * 32;
#pragma unroll
  for (int d = 0; d < 32; ++d) {
    float qf = qv[d] * iq;
    unsigned short qh = f2bf(qf);
    q_hi[base + d] = qh;
    q_lo[base + d] = f2bf(qf - bf2f(qh));
    float kf = kv[d] * ik;
    unsigned short kh = f2bf(kf);
    k_hi[base + d] = kh;
    k_lo[base + d] = f2bf(kf - bf2f(kh));
  }
}

// ---------------- K3: fused QK^T (split-bf16) -> exact top-512 -> softmax -> PV ----------------
// 8 waves, QT=8 rows; wave w owns row w. 32.9 KB LDS -> 4 WGs/CU.
// Scores staged in two half-row passes through one buffer; selection in registers.
__global__ __launch_bounds__(512, 8) void k_attn(const unsigned short* __restrict__ q_hi,
                                                 const unsigned short* __restrict__ q_lo,
                                                 const unsigned short* __restrict__ k_hi,
                                                 const unsigned short* __restrict__ k_lo,
                                                 const unsigned short* __restrict__ vt,
                                                 unsigned short* __restrict__ ao) {
  extern __shared__ float smem[];
  float* sc = smem;                           // [QT][HSTR] fp32 half-scores
  unsigned short* P = (unsigned short*)smem;  // [QT][PST] bf16 probs (aliases sc)
  float* red = smem;                          // [8][8][33] partials (aliases P, after barrier)
  int bid = blockIdx.x;
  int tile = bid & 255;                       // S/QT tiles per (b,h)
  int bh = bid >> 8;
  int q0 = tile * QT;
  int tid = threadIdx.x, lane = tid & 63, wid = tid >> 6;
  int l15 = lane & 15, lh = lane >> 4;
  const unsigned short* vb = vt + (size_t)bh * 32 * S_;

  // Q fragment (rows duplicated: A rows 0..7 = q rows, 8..15 dup)
  size_t qoff = ((size_t)bh * S_ + q0 + (l15 & 7)) * 32 + lh * 8;
  short8 ah = *(const short8*)(q_hi + qoff);
  short8 al = *(const short8*)(q_lo + qoff);
  size_t kbase = (size_t)bh * S_ * 32;

  float v[32];

  // ---- score halves: compute 8x1024 into sc, then waves pull their row to regs ----
#pragma unroll
  for (int hhalf = 0; hhalf < 2; ++hhalf) {
    int base_t = hhalf * HCOLS + wid * 128;   // this wave's 128-col span
    size_t ko = kbase + (size_t)(base_t + l15) * 32 + lh * 8;
    short8 khf = *(const short8*)(k_hi + ko);
    short8 klf = *(const short8*)(k_lo + ko);
    for (int nt = 0; nt < 8; ++nt) {
      short8 khn = khf, kln = klf;
      if (nt < 7) {
        size_t ko2 = kbase + (size_t)(base_t + (nt + 1) * 16 + l15) * 32 + lh * 8;
        khn = *(const short8*)(k_hi + ko2);
        kln = *(const short8*)(k_lo + ko2);
      }
      f32x4 d = {};
      d = __builtin_amdgcn_mfma_f32_16x16x32_bf16(ah, khf, d, 0, 0, 0);
      d = __builtin_amdgcn_mfma_f32_16x16x32_bf16(ah, klf, d, 0, 0, 0);
      d = __builtin_amdgcn_mfma_f32_16x16x32_bf16(al, khf, d, 0, 0, 0);
      if (lh < 2) {  // rows 0..7 valid
        int tloc = wid * 128 + nt * 16;
#pragma unroll
        for (int r = 0; r < 4; ++r)
          sc[(lh * 4 + r) * HSTR + tloc + l15] = d[r];
      }
      khf = khn; klf = kln;
    }
    __syncthreads();  // half scores complete
#pragma unroll
    for (int j = 0; j < 16; ++j)
      v[hhalf * 16 + j] = sc[wid * HSTR + lane + 64 * j];
    __syncthreads();  // all reads done; buffer reusable
  }

  // ---- selection (exact top-512) + softmax, all in registers ----
  // global col of v[j]: t = (j>>4)*1024 + 64*(j&15) + lane  (ascending j-major)
  {
    float vmax = v[0], vmin = v[0];
#pragma unroll
    for (int j = 1; j < 32; ++j) { vmax = fmaxf(vmax, v[j]); vmin = fminf(vmin, v[j]); }
#pragma unroll
    for (int m = 1; m < 64; m <<= 1) {
      vmax = fmaxf(vmax, __shfl_xor(vmax, m));
      vmin = fminf(vmin, __shfl_xor(vmin, m));
    }

    float vlo = vmin - 1e-3f, vhi = vmax;
    int clo = 2048, chi = 0;
    float T = vhi;
    bool exact = false;
    for (int it = 0; it < 48; ++it) {
      float piv;
      if (it & 1) piv = 0.5f * (vlo + vhi);
      else piv = vlo + (vhi - vlo) * (float)(clo - TOPK) / (float)(clo - chi);
      if (!(piv > vlo && piv < vhi)) piv = 0.5f * (vlo + vhi);
      if (!(piv > vlo && piv < vhi)) break;  // interval collapsed (ties)
      int c = 0;
#pragma unroll
      for (int j = 0; j < 32; ++j)
        c += (int)__popcll(__ballot(v[j] > piv));
      if (c == TOPK) { T = piv; exact = true; break; }
      if (c > TOPK) { vlo = piv; clo = c; }
      else { vhi = piv; chi = c; }
    }
    int cntGT = exact ? TOPK : chi;
    if (!exact) T = vhi;

    unsigned selbits = 0;
#pragma unroll
    for (int j = 0; j < 32; ++j)
      if (v[j] > T) selbits |= (1u << j);
    int need = TOPK - cntGT;
    if (need > 0) {
      // ties broken by lowest col index (jax top_k order)
      int base = 0;
      unsigned long long lmask = (lane == 0) ? 0ull : (~0ull >> (64 - lane));
#pragma unroll
      for (int j = 0; j < 32; ++j) {
        bool tie = (v[j] == T);
        unsigned long long m = __ballot(tie);
        int rank = base + (int)__popcll(m & lmask);
        if (tie && rank < need) selbits |= (1u << j);
        base += (int)__popcll(m);
      }
    }

    float ssum = 0.f;
#pragma unroll
    for (int j = 0; j < 32; ++j) {
      float e = ((selbits >> j) & 1u) ? __expf(v[j] - vmax) : 0.f;
      v[j] = e;
      ssum += e;
    }
#pragma unroll
    for (int m = 1; m < 64; m <<= 1) ssum += __shfl_xor(ssum, m);
    float is = 1.f / ssum;
#pragma unroll
    for (int j = 0; j < 32; ++j) {
      int t = ((j >> 4) << 10) + ((j & 15) << 6) + lane;
      P[wid * PST + t] = f2bf(v[j] * is);
    }
  }
  __syncthreads();  // P complete

  // ---- PV: out(8x32) = P(8x2048) @ V(2048x32); wave w covers t in [256w,256w+256) ----
  f32x4 acc0 = {}, acc1 = {};
  {
    int cw = wid * 256;
    int prow = (l15 & 7) * PST;
    short8 a0 = *(const short8*)(P + prow + cw + lh * 8);
    short8 b0 = *(const short8*)(vb + (size_t)l15 * S_ + cw + lh * 8);
    short8 b1 = *(const short8*)(vb + (size_t)(16 + l15) * S_ + cw + lh * 8);
    for (int kt = 0; kt < 8; ++kt) {
      short8 an = a0, b0n = b0, b1n = b1;
      if (kt < 7) {
        int t1 = cw + (kt + 1) * 32 + lh * 8;
        an = *(const short8*)(P + prow + t1);
        b0n = *(const short8*)(vb + (size_t)l15 * S_ + t1);
        b1n = *(const short8*)(vb + (size_t)(16 + l15) * S_ + t1);
      }
      acc0 = __builtin_amdgcn_mfma_f32_16x16x32_bf16(a0, b0, acc0, 0, 0, 0);
      acc1 = __builtin_amdgcn_mfma_f32_16x16x32_bf16(a0, b1, acc1, 0, 0, 0);
      a0 = an; b0 = b0n; b1 = b1n;
    }
  }
  __syncthreads();  // P dead; red region (aliases P) safe to write
  if (lh < 2) {
#pragma unroll
    for (int r = 0; r < 4; ++r) {
      red[(wid * 8 + lh * 4 + r) * 33 + l15] = acc0[r];
      red[(wid * 8 + lh * 4 + r) * 33 + 16 + l15] = acc1[r];
    }
  }
  __syncthreads();
  if (tid < 256) {
    int row = tid >> 5, d = tid & 31;
    float s = 0.f;
#pragma unroll
    for (int w = 0; w < 8; ++w) s += red[(w * 8 + row) * 33 + d];
    ao[((size_t)bh * S_ + q0 + row) * 32 + d] = f2bf(s);
  }
}

// ---------------- K4: output projection ----------------
__global__ __launch_bounds__(256) void k_proj(const unsigned short* __restrict__ wbf,
                                              const unsigned short* __restrict__ ao,
                                              float* __restrict__ out) {
  int b = blockIdx.z;
  int m0 = blockIdx.y * 64, n0 = blockIdx.x * 64;
  int tid = threadIdx.x, lane = tid & 63, wid = tid >> 6;
  int l15 = lane & 15, lh = lane >> 4;
  int wm = (wid >> 1) * 32, wn = (wid & 1) * 32;
  const unsigned short* aob = ao + (size_t)b * H_ * S_ * 32;
  f32x4 acc[2][2] = {};
  int mA = m0 + wm + l15;
  int nB = n0 + wn + l15;
  for (int k0 = 0; k0 < C_; k0 += 32) {
    int kk = k0 + lh * 8;
    int hh = kk >> 5;
    int dd = kk & 31;
    short8 a0 = *(const short8*)(wbf + (size_t)mA * C_ + kk);
    short8 a1 = *(const short8*)(wbf + (size_t)(mA + 16) * C_ + kk);
    short8 b0 = *(const short8*)(aob + ((size_t)hh * S_ + nB) * 32 + dd);
    short8 b1 = *(const short8*)(aob + ((size_t)hh * S_ + nB + 16) * 32 + dd);
    acc[0][0] = __builtin_amdgcn_mfma_f32_16x16x32_bf16(a0, b0, acc[0][0], 0, 0, 0);
    acc[0][1] = __builtin_amdgcn_mfma_f32_16x16x32_bf16(a0, b1, acc[0][1], 0, 0, 0);
    acc[1][0] = __builtin_amdgcn_mfma_f32_16x16x32_bf16(a1, b0, acc[1][0], 0, 0, 0);
    acc[1][1] = __builtin_amdgcn_mfma_f32_16x16x32_bf16(a1, b1, acc[1][1], 0, 0, 0);
  }
  float* ob = out + (size_t)b * C_ * S_;
#pragma unroll
  for (int i = 0; i < 2; ++i)
#pragma unroll
    for (int j = 0; j < 2; ++j)
#pragma unroll
      for (int r = 0; r < 4; ++r) {
        int row = m0 + wm + i * 16 + lh * 4 + r;
        int col = n0 + wn + j * 16 + l15;
        ob[(size_t)row * S_ + col] = acc[i][j][r];
      }
}

extern "C" void kernel_launch(void* const* d_in, const int* in_sizes, int n_in,
                              void* d_out, int out_size, void* d_ws, size_t ws_size,
                              hipStream_t stream) {
  const float* x = (const float*)d_in[0];
  const float* wqkv = (const float*)d_in[1];
  const float* wdw = (const float*)d_in[2];
  const float* wproj = (const float*)d_in[3];
  const float* temp = (const float*)d_in[4];
  float* out = (float*)d_out;

  char* ws = (char*)d_ws;
  size_t off = 0;
  auto alloc = [&](size_t bytes) -> void* {
    void* p = ws + off;
    off += (bytes + 255) & ~(size_t)255;
    return p;
  };
  unsigned short* x_hi     = (unsigned short*)alloc((size_t)B_ * S_ * C_ * 2);
  unsigned short* x_lo     = (unsigned short*)alloc((size_t)B_ * S_ * C_ * 2);
  unsigned short* wq_hi    = (unsigned short*)alloc((size_t)O3_ * C_ * 2);
  unsigned short* wq_lo    = (unsigned short*)alloc((size_t)O3_ * C_ * 2);
  unsigned short* wproj_bf = (unsigned short*)alloc((size_t)C_ * C_ * 2);
  float*          raw      = (float*)alloc((size_t)B_ * O3_ * S_ * 4);
  unsigned short* k_hi     = (unsigned short*)alloc((size_t)B_ * H_ * S_ * 32 * 2);
  unsigned short* k_lo     = (unsigned short*)alloc((size_t)B_ * H_ * S_ * 32 * 2);
  unsigned short* vt       = (unsigned short*)alloc((size_t)B_ * H_ * 32 * S_ * 2);
  unsigned short* q_hi     = x_hi;                 // alias (x dead after k_qkv)
  unsigned short* q_lo     = x_lo;                 // alias
  unsigned short* ao       = (unsigned short*)raw; // alias (raw dead after k_dwnorm)

  (void)hipFuncSetAttribute(reinterpret_cast<const void*>(k_attn),
                            hipFuncAttributeMaxDynamicSharedMemorySize, (int)K3_LDS_BYTES);

  k_convw<<<dim3((O3_ * C_ + 255) / 256), dim3(256), 0, stream>>>(wqkv, wproj, wq_hi, wq_lo, wproj_bf);
  k_xt<<<dim3(S_ / 32, C_ / 32, B_), dim3(32, 8), 0, stream>>>(x, x_hi, x_lo);
  k_qkv<<<dim3(S_ / 64, O3_ / 64, B_), dim3(256), 0, stream>>>(wq_hi, wq_lo, x_hi, x_lo, raw);
  k_dwnorm<<<dim3(S_ / 256, H_, B_), dim3(256), 0, stream>>>(raw, wdw, temp, q_hi, q_lo, k_hi, k_lo, vt);
  k_attn<<<dim3(B_ * H_ * (S_ / QT)), dim3(512), K3_LDS_BYTES, stream>>>(q_hi, q_lo, k_hi, k_lo, vt, ao);
  k_proj<<<dim3(S_ / 64, C_ / 64, B_), dim3(256), 0, stream>>>(wproj_bf, ao, out);
}

// Round 5
// 344.651 us; speedup vs baseline: 1.8805x; 1.1137x over previous
//
#include <hip/hip_runtime.h>
#include <math.h>

typedef __attribute__((ext_vector_type(8))) short short8;
typedef __attribute__((ext_vector_type(4))) float f32x4;

#define DEV __device__ __forceinline__

static constexpr int B_ = 4, C_ = 256, S_ = 2048, H_ = 8, O3_ = 768;
static constexpr int TOPK = 512;
static constexpr int QT = 8;            // q rows per workgroup in attention
static constexpr int HCOLS = 1024;      // score cols staged per pass
static constexpr int HSTR = 1028;       // fp32 score row stride (half buffer)
static constexpr int PST = 2056;        // bf16 P row stride; 2056*2=4112 B (16B aligned)
// LDS: one region, 8*1028*4 = 32896 B. P (8*2056*2=32896 B) aliases it exactly.
// red (8*8*33*4 = 8448 B) aliases P after a barrier. -> 4 WGs/CU.
static constexpr size_t K3_LDS_BYTES = (size_t)QT * HSTR * 4;  // 32896 B

DEV unsigned short f2bf(float f) {
  unsigned u = __float_as_uint(f);
  return (unsigned short)((u + 0x7FFFu + ((u >> 16) & 1u)) >> 16);  // RNE
}
DEV float bf2f(unsigned short h) { return __uint_as_float(((unsigned)h) << 16); }

// ---------------- K0a: weights -> bf16 hi/lo (qkv), bf16 (proj) ----------------
__global__ void k_convw(const float* __restrict__ wqkv, const float* __restrict__ wproj,
                        unsigned short* __restrict__ wq_hi, unsigned short* __restrict__ wq_lo,
                        unsigned short* __restrict__ wproj_bf) {
  int i = blockIdx.x * 256 + threadIdx.x;
  if (i < O3_ * C_) {
    float f = wqkv[i];
    unsigned short h = f2bf(f);
    wq_hi[i] = h;
    wq_lo[i] = f2bf(f - bf2f(h));
  }
  if (i < C_ * C_) wproj_bf[i] = f2bf(wproj[i]);
}

// ---------------- K0b: transpose x [b][c][s] -> xT hi/lo bf16 [b][s][c] ----------------
__global__ void k_xt(const float* __restrict__ x, unsigned short* __restrict__ xT_hi,
                     unsigned short* __restrict__ xT_lo) {
  __shared__ float t[32][33];
  int b = blockIdx.z;
  int c0 = blockIdx.y * 32, s0 = blockIdx.x * 32;
  int tx = threadIdx.x, ty = threadIdx.y;
  const float* xb = x + (size_t)b * C_ * S_;
#pragma unroll
  for (int j = 0; j < 4; ++j)
    t[ty + 8 * j][tx] = xb[(size_t)(c0 + ty + 8 * j) * S_ + s0 + tx];
  __syncthreads();
  unsigned short* hb = xT_hi + (size_t)b * S_ * C_;
  unsigned short* lb = xT_lo + (size_t)b * S_ * C_;
#pragma unroll
  for (int j = 0; j < 4; ++j) {
    float f = t[tx][ty + 8 * j];
    unsigned short h = f2bf(f);
    size_t o = (size_t)(s0 + ty + 8 * j) * C_ + c0 + tx;
    hb[o] = h;
    lb[o] = f2bf(f - bf2f(h));
  }
}

// ---------------- K1: qkv_raw = W_qkv @ x  (split-bf16 3-pass MFMA, ~fp32 accurate) ----------------
__global__ __launch_bounds__(256) void k_qkv(const unsigned short* __restrict__ w_hi,
                                             const unsigned short* __restrict__ w_lo,
                                             const unsigned short* __restrict__ x_hi,
                                             const unsigned short* __restrict__ x_lo,
                                             float* __restrict__ raw) {
  int b = blockIdx.z;
  int m0 = blockIdx.y * 64, n0 = blockIdx.x * 64;
  int tid = threadIdx.x, lane = tid & 63, wid = tid >> 6;
  int l15 = lane & 15, lh = lane >> 4;
  int wm = (wid >> 1) * 32, wn = (wid & 1) * 32;
  const unsigned short* xhb = x_hi + (size_t)b * S_ * C_;
  const unsigned short* xlb = x_lo + (size_t)b * S_ * C_;
  f32x4 acc[2][2] = {};
  int mA = m0 + wm + l15;
  int nB = n0 + wn + l15;
  for (int k0 = 0; k0 < C_; k0 += 32) {
    int kk = k0 + lh * 8;
    short8 a0h = *(const short8*)(w_hi + (size_t)mA * C_ + kk);
    short8 a1h = *(const short8*)(w_hi + (size_t)(mA + 16) * C_ + kk);
    short8 a0l = *(const short8*)(w_lo + (size_t)mA * C_ + kk);
    short8 a1l = *(const short8*)(w_lo + (size_t)(mA + 16) * C_ + kk);
    short8 b0h = *(const short8*)(xhb + (size_t)nB * C_ + kk);
    short8 b1h = *(const short8*)(xhb + (size_t)(nB + 16) * C_ + kk);
    short8 b0l = *(const short8*)(xlb + (size_t)nB * C_ + kk);
    short8 b1l = *(const short8*)(xlb + (size_t)(nB + 16) * C_ + kk);
    acc[0][0] = __builtin_amdgcn_mfma_f32_16x16x32_bf16(a0h, b0h, acc[0][0], 0, 0, 0);
    acc[0][1] = __builtin_amdgcn_mfma_f32_16x16x32_bf16(a0h, b1h, acc[0][1], 0, 0, 0);
    acc[1][0] = __builtin_amdgcn_mfma_f32_16x16x32_bf16(a1h, b0h, acc[1][0], 0, 0, 0);
    acc[1][1] = __builtin_amdgcn_mfma_f32_16x16x32_bf16(a1h, b1h, acc[1][1], 0, 0, 0);
    acc[0][0] = __builtin_amdgcn_mfma_f32_16x16x32_bf16(a0h, b0l, acc[0][0], 0, 0, 0);
    acc[0][1] = __builtin_amdgcn_mfma_f32_16x16x32_bf16(a0h, b1l, acc[0][1], 0, 0, 0);
    acc[1][0] = __builtin_amdgcn_mfma_f32_16x16x32_bf16(a1h, b0l, acc[1][0], 0, 0, 0);
    acc[1][1] = __builtin_amdgcn_mfma_f32_16x16x32_bf16(a1h, b1l, acc[1][1], 0, 0, 0);
    acc[0][0] = __builtin_amdgcn_mfma_f32_16x16x32_bf16(a0l, b0h, acc[0][0], 0, 0, 0);
    acc[0][1] = __builtin_amdgcn_mfma_f32_16x16x32_bf16(a0l, b1h, acc[0][1], 0, 0, 0);
    acc[1][0] = __builtin_amdgcn_mfma_f32_16x16x32_bf16(a1l, b0h, acc[1][0], 0, 0, 0);
    acc[1][1] = __builtin_amdgcn_mfma_f32_16x16x32_bf16(a1l, b1h, acc[1][1], 0, 0, 0);
  }
  float* rawb = raw + (size_t)b * O3_ * S_;
#pragma unroll
  for (int i = 0; i < 2; ++i)
#pragma unroll
    for (int j = 0; j < 2; ++j)
#pragma unroll
      for (int r = 0; r < 4; ++r) {
        int row = m0 + wm + i * 16 + lh * 4 + r;
        int col = n0 + wn + j * 16 + l15;
        rawb[(size_t)row * S_ + col] = acc[i][j][r];
      }
}

// ---------------- K2: depthwise conv + head split + l2norm (+temperature fold) ----------------
DEV float conv3(const float* __restrict__ rp, const float* __restrict__ w, int s) {
  float a = (s > 0) ? rp[s - 1] : 0.f;
  float b = rp[s];
  float c = (s < S_ - 1) ? rp[s + 1] : 0.f;
  return w[0] * a + w[1] * b + w[2] * c;
}

__global__ __launch_bounds__(256) void k_dwnorm(const float* __restrict__ raw,
                                                const float* __restrict__ wdw,
                                                const float* __restrict__ temp,
                                                unsigned short* __restrict__ q_hi,
                                                unsigned short* __restrict__ q_lo,
                                                unsigned short* __restrict__ k_hi,
                                                unsigned short* __restrict__ k_lo,
                                                unsigned short* __restrict__ vt) {
  int b = blockIdx.z, h = blockIdx.y;
  int s = blockIdx.x * 256 + threadIdx.x;
  const float* rawb = raw + (size_t)b * O3_ * S_;
  float tph = temp[h];
  float qv[32], kv[32];
  float sq = 0.f, sk = 0.f;
  size_t bh = (size_t)(b * H_ + h);
#pragma unroll
  for (int d = 0; d < 32; ++d) {
    int oq = h * 32 + d;
    float q = conv3(rawb + (size_t)oq * S_, wdw + oq * 3, s);
    qv[d] = q; sq += q * q;
    int ok = oq + 256;
    float k = conv3(rawb + (size_t)ok * S_, wdw + ok * 3, s);
    kv[d] = k; sk += k * k;
    int ov = oq + 512;
    float v = conv3(rawb + (size_t)ov * S_, wdw + ov * 3, s);
    vt[(bh * 32 + d) * S_ + s] = f2bf(v);
  }
  float iq = tph / fmaxf(sqrtf(sq), 1e-12f);
  float ik = 1.f / fmaxf(sqrtf(sk), 1e-12f);
  size_t base = (bh * S_ + s) * 32;
#pragma unroll
  for (int d = 0; d < 32; ++d) {
    float qf = qv[d] * iq;
    unsigned short qh = f2bf(qf);
    q_hi[base + d] = qh;
    q_lo[base + d] = f2bf(qf - bf2f(qh));
    float kf = kv[d] * ik;
    unsigned short kh = f2bf(kf);
    k_hi[base + d] = kh;
    k_lo[base + d] = f2bf(kf - bf2f(kh));
  }
}

// ---------------- K3: fused QK^T (split-bf16) -> exact top-512 -> softmax -> PV ----------------
// 8 waves, QT=8 rows; wave w owns row w. 32.9 KB LDS -> 4 WGs/CU.
// Scores staged in two half-row passes; selection in registers via Illinois false position.
__global__ __launch_bounds__(512, 8) void k_attn(const unsigned short* __restrict__ q_hi,
                                                 const unsigned short* __restrict__ q_lo,
                                                 const unsigned short* __restrict__ k_hi,
                                                 const unsigned short* __restrict__ k_lo,
                                                 const unsigned short* __restrict__ vt,
                                                 unsigned short* __restrict__ ao) {
  extern __shared__ float smem[];
  float* sc = smem;                           // [QT][HSTR] fp32 half-scores
  unsigned short* P = (unsigned short*)smem;  // [QT][PST] bf16 probs (aliases sc)
  float* red = smem;                          // [8][8][33] partials (aliases P, after barrier)
  int bid = blockIdx.x;
  int tile = bid & 255;                       // S/QT tiles per (b,h)
  int bh = bid >> 8;
  int q0 = tile * QT;
  int tid = threadIdx.x, lane = tid & 63, wid = tid >> 6;
  int l15 = lane & 15, lh = lane >> 4;
  const unsigned short* vb = vt + (size_t)bh * 32 * S_;

  // Q fragment (rows duplicated: A rows 0..7 = q rows, 8..15 dup)
  size_t qoff = ((size_t)bh * S_ + q0 + (l15 & 7)) * 32 + lh * 8;
  short8 ah = *(const short8*)(q_hi + qoff);
  short8 al = *(const short8*)(q_lo + qoff);
  size_t kbase = (size_t)bh * S_ * 32;

  float v[32];

  // ---- score halves: compute 8x1024 into sc, then waves pull their row to regs ----
#pragma unroll
  for (int hhalf = 0; hhalf < 2; ++hhalf) {
    int base_t = hhalf * HCOLS + wid * 128;   // this wave's 128-col span
    const unsigned short* kh_p = k_hi + kbase + (size_t)(base_t + l15) * 32 + lh * 8;
    const unsigned short* kl_p = k_lo + kbase + (size_t)(base_t + l15) * 32 + lh * 8;
    // depth-2 prefetch: frags for nt and nt+1 in flight
    short8 kh0 = *(const short8*)(kh_p);
    short8 kl0 = *(const short8*)(kl_p);
    short8 kh1 = *(const short8*)(kh_p + 512);   // +16 rows * 32
    short8 kl1 = *(const short8*)(kl_p + 512);
    for (int nt = 0; nt < 8; ++nt) {
      short8 kh2 = kh1, kl2 = kl1;
      if (nt < 6) {
        kh2 = *(const short8*)(kh_p + (nt + 2) * 512);
        kl2 = *(const short8*)(kl_p + (nt + 2) * 512);
      }
      f32x4 d = {};
      d = __builtin_amdgcn_mfma_f32_16x16x32_bf16(ah, kh0, d, 0, 0, 0);
      d = __builtin_amdgcn_mfma_f32_16x16x32_bf16(ah, kl0, d, 0, 0, 0);
      d = __builtin_amdgcn_mfma_f32_16x16x32_bf16(al, kh0, d, 0, 0, 0);
      if (lh < 2) {  // rows 0..7 valid
        int tloc = wid * 128 + nt * 16;
#pragma unroll
        for (int r = 0; r < 4; ++r)
          sc[(lh * 4 + r) * HSTR + tloc + l15] = d[r];
      }
      kh0 = kh1; kl0 = kl1; kh1 = kh2; kl1 = kl2;
    }
    __syncthreads();  // half scores complete
#pragma unroll
    for (int j = 0; j < 16; ++j)
      v[hhalf * 16 + j] = sc[wid * HSTR + lane + 64 * j];
    __syncthreads();  // all reads done; buffer reusable
  }

  // ---- selection (exact top-512) + softmax, all in registers ----
  // global col of v[j]: t = (j>>4)*1024 + 64*(j&15) + lane  (ascending j-major)
  {
    float vmax = v[0], vmin = v[0];
#pragma unroll
    for (int j = 1; j < 32; ++j) { vmax = fmaxf(vmax, v[j]); vmin = fminf(vmin, v[j]); }
#pragma unroll
    for (int m = 1; m < 64; m <<= 1) {
      vmax = fmaxf(vmax, __shfl_xor(vmax, m));
      vmin = fminf(vmin, __shfl_xor(vmin, m));
    }

    // Illinois false position on f(piv) = count(v > piv) - TOPK.
    // Invariant: count(>vlo) > TOPK >= count(>vhi).
    float vlo = vmin - 1e-3f, vhi = vmax;
    float flo = (float)(2048 - TOPK), fhi = (float)(0 - TOPK);
    int chi = 0;          // count at vhi
    float T = vhi;
    bool exact = false;
    int lastside = 0;     // +1: moved lo, -1: moved hi
    for (int it = 0; it < 32; ++it) {
      float piv = vhi - fhi * (vhi - vlo) / (fhi - flo);
      if (!(piv > vlo && piv < vhi)) piv = 0.5f * (vlo + vhi);
      if (!(piv > vlo && piv < vhi)) break;  // interval collapsed (ties)
      int c = 0;
#pragma unroll
      for (int j = 0; j < 32; ++j)
        c += (int)__popcll(__ballot(v[j] > piv));
      if (c == TOPK) { T = piv; exact = true; break; }
      if (c > TOPK) {
        if (lastside == 1) fhi *= 0.5f;  // Illinois: hi endpoint retained again
        vlo = piv; flo = (float)(c - TOPK); lastside = 1;
      } else {
        if (lastside == -1) flo *= 0.5f;
        vhi = piv; fhi = (float)(c - TOPK); chi = c; lastside = -1;
      }
    }
    int cntGT = exact ? TOPK : chi;
    if (!exact) T = vhi;

    unsigned selbits = 0;
#pragma unroll
    for (int j = 0; j < 32; ++j)
      if (v[j] > T) selbits |= (1u << j);
    int need = TOPK - cntGT;
    if (need > 0) {
      // ties broken by lowest col index (jax top_k order)
      int base = 0;
      unsigned long long lmask = (lane == 0) ? 0ull : (~0ull >> (64 - lane));
#pragma unroll
      for (int j = 0; j < 32; ++j) {
        bool tie = (v[j] == T);
        unsigned long long m = __ballot(tie);
        int rank = base + (int)__popcll(m & lmask);
        if (tie && rank < need) selbits |= (1u << j);
        base += (int)__popcll(m);
      }
    }

    float ssum = 0.f;
#pragma unroll
    for (int j = 0; j < 32; ++j) {
      float e = ((selbits >> j) & 1u) ? __expf(v[j] - vmax) : 0.f;
      v[j] = e;
      ssum += e;
    }
#pragma unroll
    for (int m = 1; m < 64; m <<= 1) ssum += __shfl_xor(ssum, m);
    float is = 1.f / ssum;
#pragma unroll
    for (int j = 0; j < 32; ++j) {
      int t = ((j >> 4) << 10) + ((j & 15) << 6) + lane;
      P[wid * PST + t] = f2bf(v[j] * is);
    }
  }
  __syncthreads();  // P complete

  // ---- PV: out(8x32) = P(8x2048) @ V(2048x32); wave w covers t in [256w,256w+256) ----
  f32x4 acc0 = {}, acc1 = {};
  {
    int cw = wid * 256;
    int prow = (l15 & 7) * PST;
    const unsigned short* v0p = vb + (size_t)l15 * S_ + cw + lh * 8;
    const unsigned short* v1p = vb + (size_t)(16 + l15) * S_ + cw + lh * 8;
    const unsigned short* pp = P + prow + cw + lh * 8;
    // depth-2 prefetch
    short8 a0 = *(const short8*)(pp);
    short8 b0 = *(const short8*)(v0p);
    short8 b1 = *(const short8*)(v1p);
    short8 a0n = *(const short8*)(pp + 32);
    short8 b0n = *(const short8*)(v0p + 32);
    short8 b1n = *(const short8*)(v1p + 32);
    for (int kt = 0; kt < 8; ++kt) {
      short8 a2 = a0n, b02 = b0n, b12 = b1n;
      if (kt < 6) {
        a2 = *(const short8*)(pp + (kt + 2) * 32);
        b02 = *(const short8*)(v0p + (kt + 2) * 32);
        b12 = *(const short8*)(v1p + (kt + 2) * 32);
      }
      acc0 = __builtin_amdgcn_mfma_f32_16x16x32_bf16(a0, b0, acc0, 0, 0, 0);
      acc1 = __builtin_amdgcn_mfma_f32_16x16x32_bf16(a0, b1, acc1, 0, 0, 0);
      a0 = a0n; b0 = b0n; b1 = b1n;
      a0n = a2; b0n = b02; b1n = b12;
    }
  }
  __syncthreads();  // P dead; red region (aliases P) safe to write
  if (lh < 2) {
#pragma unroll
    for (int r = 0; r < 4; ++r) {
      red[(wid * 8 + lh * 4 + r) * 33 + l15] = acc0[r];
      red[(wid * 8 + lh * 4 + r) * 33 + 16 + l15] = acc1[r];
    }
  }
  __syncthreads();
  if (tid < 256) {
    int row = tid >> 5, d = tid & 31;
    float s = 0.f;
#pragma unroll
    for (int w = 0; w < 8; ++w) s += red[(w * 8 + row) * 33 + d];
    ao[((size_t)bh * S_ + q0 + row) * 32 + d] = f2bf(s);
  }
}

// ---------------- K4: output projection ----------------
__global__ __launch_bounds__(256) void k_proj(const unsigned short* __restrict__ wbf,
                                              const unsigned short* __restrict__ ao,
                                              float* __restrict__ out) {
  int b = blockIdx.z;
  int m0 = blockIdx.y * 64, n0 = blockIdx.x * 64;
  int tid = threadIdx.x, lane = tid & 63, wid = tid >> 6;
  int l15 = lane & 15, lh = lane >> 4;
  int wm = (wid >> 1) * 32, wn = (wid & 1) * 32;
  const unsigned short* aob = ao + (size_t)b * H_ * S_ * 32;
  f32x4 acc[2][2] = {};
  int mA = m0 + wm + l15;
  int nB = n0 + wn + l15;
  for (int k0 = 0; k0 < C_; k0 += 32) {
    int kk = k0 + lh * 8;
    int hh = kk >> 5;
    int dd = kk & 31;
    short8 a0 = *(const short8*)(wbf + (size_t)mA * C_ + kk);
    short8 a1 = *(const short8*)(wbf + (size_t)(mA + 16) * C_ + kk);
    short8 b0 = *(const short8*)(aob + ((size_t)hh * S_ + nB) * 32 + dd);
    short8 b1 = *(const short8*)(aob + ((size_t)hh * S_ + nB + 16) * 32 + dd);
    acc[0][0] = __builtin_amdgcn_mfma_f32_16x16x32_bf16(a0, b0, acc[0][0], 0, 0, 0);
    acc[0][1] = __builtin_amdgcn_mfma_f32_16x16x32_bf16(a0, b1, acc[0][1], 0, 0, 0);
    acc[1][0] = __builtin_amdgcn_mfma_f32_16x16x32_bf16(a1, b0, acc[1][0], 0, 0, 0);
    acc[1][1] = __builtin_amdgcn_mfma_f32_16x16x32_bf16(a1, b1, acc[1][1], 0, 0, 0);
  }
  float* ob = out + (size_t)b * C_ * S_;
#pragma unroll
  for (int i = 0; i < 2; ++i)
#pragma unroll
    for (int j = 0; j < 2; ++j)
#pragma unroll
      for (int r = 0; r < 4; ++r) {
        int row = m0 + wm + i * 16 + lh * 4 + r;
        int col = n0 + wn + j * 16 + l15;
        ob[(size_t)row * S_ + col] = acc[i][j][r];
      }
}

extern "C" void kernel_launch(void* const* d_in, const int* in_sizes, int n_in,
                              void* d_out, int out_size, void* d_ws, size_t ws_size,
                              hipStream_t stream) {
  const float* x = (const float*)d_in[0];
  const float* wqkv = (const float*)d_in[1];
  const float* wdw = (const float*)d_in[2];
  const float* wproj = (const float*)d_in[3];
  const float* temp = (const float*)d_in[4];
  float* out = (float*)d_out;

  char* ws = (char*)d_ws;
  size_t off = 0;
  auto alloc = [&](size_t bytes) -> void* {
    void* p = ws + off;
    off += (bytes + 255) & ~(size_t)255;
    return p;
  };
  unsigned short* x_hi     = (unsigned short*)alloc((size_t)B_ * S_ * C_ * 2);
  unsigned short* x_lo     = (unsigned short*)alloc((size_t)B_ * S_ * C_ * 2);
  unsigned short* wq_hi    = (unsigned short*)alloc((size_t)O3_ * C_ * 2);
  unsigned short* wq_lo    = (unsigned short*)alloc((size_t)O3_ * C_ * 2);
  unsigned short* wproj_bf = (unsigned short*)alloc((size_t)C_ * C_ * 2);
  float*          raw      = (float*)alloc((size_t)B_ * O3_ * S_ * 4);
  unsigned short* k_hi     = (unsigned short*)alloc((size_t)B_ * H_ * S_ * 32 * 2);
  unsigned short* k_lo     = (unsigned short*)alloc((size_t)B_ * H_ * S_ * 32 * 2);
  unsigned short* vt       = (unsigned short*)alloc((size_t)B_ * H_ * 32 * S_ * 2);
  unsigned short* q_hi     = x_hi;                 // alias (x dead after k_qkv)
  unsigned short* q_lo     = x_lo;                 // alias
  unsigned short* ao       = (unsigned short*)raw; // alias (raw dead after k_dwnorm)

  (void)hipFuncSetAttribute(reinterpret_cast<const void*>(k_attn),
                            hipFuncAttributeMaxDynamicSharedMemorySize, (int)K3_LDS_BYTES);

  k_convw<<<dim3((O3_ * C_ + 255) / 256), dim3(256), 0, stream>>>(wqkv, wproj, wq_hi, wq_lo, wproj_bf);
  k_xt<<<dim3(S_ / 32, C_ / 32, B_), dim3(32, 8), 0, stream>>>(x, x_hi, x_lo);
  k_qkv<<<dim3(S_ / 64, O3_ / 64, B_), dim3(256), 0, stream>>>(wq_hi, wq_lo, x_hi, x_lo, raw);
  k_dwnorm<<<dim3(S_ / 256, H_, B_), dim3(256), 0, stream>>>(raw, wdw, temp, q_hi, q_lo, k_hi, k_lo, vt);
  k_attn<<<dim3(B_ * H_ * (S_ / QT)), dim3(512), K3_LDS_BYTES, stream>>>(q_hi, q_lo, k_hi, k_lo, vt, ao);
  k_proj<<<dim3(S_ / 64, C_ / 64, B_), dim3(256), 0, stream>>>(wproj_bf, ao, out);
}

// Round 7
// 293.280 us; speedup vs baseline: 2.2099x; 1.1752x over previous
//
#include <hip/hip_runtime.h>
#include <math.h>

typedef __attribute__((ext_vector_type(8))) short short8;
typedef __attribute__((ext_vector_type(4))) float f32x4;

#define DEV __device__ __forceinline__

static constexpr int B_ = 4, C_ = 256, S_ = 2048, H_ = 8, O3_ = 768;
static constexpr int TOPK = 512;
static constexpr int QT = 16;           // q rows per workgroup in attention
static constexpr int HCOLS = 1024;      // score cols staged per pass
static constexpr int HSTR = 1028;       // fp32 score row stride (half buffer)
static constexpr int PSTH = 1024;       // bf16 P half row stride; rows 2048B-aligned -> XOR swizzle bijective
// LDS: one region, 16*1028*4 = 65792 B. Half-P (16*1024*2=32768 B) aliases it.
// red (flat, <34 KB) aliases after P dead. -> 2 WGs/CU * 16 waves = 32 waves/CU.
static constexpr size_t K3_LDS_BYTES = (size_t)QT * HSTR * 4;  // 65792 B

DEV unsigned short f2bf(float f) {
  unsigned u = __float_as_uint(f);
  return (unsigned short)((u + 0x7FFFu + ((u >> 16) & 1u)) >> 16);  // RNE
}
DEV float bf2f(unsigned short h) { return __uint_as_float(((unsigned)h) << 16); }

// ---------------- K0a: weights -> bf16 hi/lo (qkv), bf16 (proj) ----------------
__global__ void k_convw(const float* __restrict__ wqkv, const float* __restrict__ wproj,
                        unsigned short* __restrict__ wq_hi, unsigned short* __restrict__ wq_lo,
                        unsigned short* __restrict__ wproj_bf) {
  int i = blockIdx.x * 256 + threadIdx.x;
  if (i < O3_ * C_) {
    float f = wqkv[i];
    unsigned short h = f2bf(f);
    wq_hi[i] = h;
    wq_lo[i] = f2bf(f - bf2f(h));
  }
  if (i < C_ * C_) wproj_bf[i] = f2bf(wproj[i]);
}

// ---------------- K0b: transpose x [b][c][s] -> xT hi/lo bf16 [b][s][c] ----------------
__global__ void k_xt(const float* __restrict__ x, unsigned short* __restrict__ xT_hi,
                     unsigned short* __restrict__ xT_lo) {
  __shared__ float t[32][33];
  int b = blockIdx.z;
  int c0 = blockIdx.y * 32, s0 = blockIdx.x * 32;
  int tx = threadIdx.x, ty = threadIdx.y;
  const float* xb = x + (size_t)b * C_ * S_;
#pragma unroll
  for (int j = 0; j < 4; ++j)
    t[ty + 8 * j][tx] = xb[(size_t)(c0 + ty + 8 * j) * S_ + s0 + tx];
  __syncthreads();
  unsigned short* hb = xT_hi + (size_t)b * S_ * C_;
  unsigned short* lb = xT_lo + (size_t)b * S_ * C_;
#pragma unroll
  for (int j = 0; j < 4; ++j) {
    float f = t[tx][ty + 8 * j];
    unsigned short h = f2bf(f);
    size_t o = (size_t)(s0 + ty + 8 * j) * C_ + c0 + tx;
    hb[o] = h;
    lb[o] = f2bf(f - bf2f(h));
  }
}

// ---------------- K1: qkv_raw = W_qkv @ x  (split-bf16 3-pass MFMA, ~fp32 accurate) ----------------
__global__ __launch_bounds__(256) void k_qkv(const unsigned short* __restrict__ w_hi,
                                             const unsigned short* __restrict__ w_lo,
                                             const unsigned short* __restrict__ x_hi,
                                             const unsigned short* __restrict__ x_lo,
                                             float* __restrict__ raw) {
  int b = blockIdx.z;
  int m0 = blockIdx.y * 64, n0 = blockIdx.x * 64;
  int tid = threadIdx.x, lane = tid & 63, wid = tid >> 6;
  int l15 = lane & 15, lh = lane >> 4;
  int wm = (wid >> 1) * 32, wn = (wid & 1) * 32;
  const unsigned short* xhb = x_hi + (size_t)b * S_ * C_;
  const unsigned short* xlb = x_lo + (size_t)b * S_ * C_;
  f32x4 acc[2][2] = {};
  int mA = m0 + wm + l15;
  int nB = n0 + wn + l15;
  for (int k0 = 0; k0 < C_; k0 += 32) {
    int kk = k0 + lh * 8;
    short8 a0h = *(const short8*)(w_hi + (size_t)mA * C_ + kk);
    short8 a1h = *(const short8*)(w_hi + (size_t)(mA + 16) * C_ + kk);
    short8 a0l = *(const short8*)(w_lo + (size_t)mA * C_ + kk);
    short8 a1l = *(const short8*)(w_lo + (size_t)(mA + 16) * C_ + kk);
    short8 b0h = *(const short8*)(xhb + (size_t)nB * C_ + kk);
    short8 b1h = *(const short8*)(xhb + (size_t)(nB + 16) * C_ + kk);
    short8 b0l = *(const short8*)(xlb + (size_t)nB * C_ + kk);
    short8 b1l = *(const short8*)(xlb + (size_t)(nB + 16) * C_ + kk);
    acc[0][0] = __builtin_amdgcn_mfma_f32_16x16x32_bf16(a0h, b0h, acc[0][0], 0, 0, 0);
    acc[0][1] = __builtin_amdgcn_mfma_f32_16x16x32_bf16(a0h, b1h, acc[0][1], 0, 0, 0);
    acc[1][0] = __builtin_amdgcn_mfma_f32_16x16x32_bf16(a1h, b0h, acc[1][0], 0, 0, 0);
    acc[1][1] = __builtin_amdgcn_mfma_f32_16x16x32_bf16(a1h, b1h, acc[1][1], 0, 0, 0);
    acc[0][0] = __builtin_amdgcn_mfma_f32_16x16x32_bf16(a0h, b0l, acc[0][0], 0, 0, 0);
    acc[0][1] = __builtin_amdgcn_mfma_f32_16x16x32_bf16(a0h, b1l, acc[0][1], 0, 0, 0);
    acc[1][0] = __builtin_amdgcn_mfma_f32_16x16x32_bf16(a1h, b0l, acc[1][0], 0, 0, 0);
    acc[1][1] = __builtin_amdgcn_mfma_f32_16x16x32_bf16(a1h, b1l, acc[1][1], 0, 0, 0);
    acc[0][0] = __builtin_amdgcn_mfma_f32_16x16x32_bf16(a0l, b0h, acc[0][0], 0, 0, 0);
    acc[0][1] = __builtin_amdgcn_mfma_f32_16x16x32_bf16(a0l, b1h, acc[0][1], 0, 0, 0);
    acc[1][0] = __builtin_amdgcn_mfma_f32_16x16x32_bf16(a1l, b0h, acc[1][0], 0, 0, 0);
    acc[1][1] = __builtin_amdgcn_mfma_f32_16x16x32_bf16(a1l, b1h, acc[1][1], 0, 0, 0);
  }
  float* rawb = raw + (size_t)b * O3_ * S_;
#pragma unroll
  for (int i = 0; i < 2; ++i)
#pragma unroll
    for (int j = 0; j < 2; ++j)
#pragma unroll
      for (int r = 0; r < 4; ++r) {
        int row = m0 + wm + i * 16 + lh * 4 + r;
        int col = n0 + wn + j * 16 + l15;
        rawb[(size_t)row * S_ + col] = acc[i][j][r];
      }
}

// ---------------- K2: depthwise conv + head split + l2norm (+temperature fold) ----------------
DEV float conv3(const float* __restrict__ rp, const float* __restrict__ w, int s) {
  float a = (s > 0) ? rp[s - 1] : 0.f;
  float b = rp[s];
  float c = (s < S_ - 1) ? rp[s + 1] : 0.f;
  return w[0] * a + w[1] * b + w[2] * c;
}

__global__ __launch_bounds__(256) void k_dwnorm(const float* __restrict__ raw,
                                                const float* __restrict__ wdw,
                                                const float* __restrict__ temp,
                                                unsigned short* __restrict__ q_hi,
                                                unsigned short* __restrict__ q_lo,
                                                unsigned short* __restrict__ k_hi,
                                                unsigned short* __restrict__ k_lo,
                                                unsigned short* __restrict__ vt) {
  int b = blockIdx.z, h = blockIdx.y;
  int s = blockIdx.x * 256 + threadIdx.x;
  const float* rawb = raw + (size_t)b * O3_ * S_;
  float tph = temp[h];
  float qv[32], kv[32];
  float sq = 0.f, sk = 0.f;
  size_t bh = (size_t)(b * H_ + h);
#pragma unroll
  for (int d = 0; d < 32; ++d) {
    int oq = h * 32 + d;
    float q = conv3(rawb + (size_t)oq * S_, wdw + oq * 3, s);
    qv[d] = q; sq += q * q;
    int ok = oq + 256;
    float k = conv3(rawb + (size_t)ok * S_, wdw + ok * 3, s);
    kv[d] = k; sk += k * k;
    int ov = oq + 512;
    float v = conv3(rawb + (size_t)ov * S_, wdw + ov * 3, s);
    vt[(bh * 32 + d) * S_ + s] = f2bf(v);
  }
  float iq = tph / fmaxf(sqrtf(sq), 1e-12f);
  float ik = 1.f / fmaxf(sqrtf(sk), 1e-12f);
  size_t base = (bh * S_ + s) * 32;
#pragma unroll
  for (int d = 0; d < 32; ++d) {
    float qf = qv[d] * iq;
    unsigned short qh = f2bf(qf);
    q_hi[base + d] = qh;
    q_lo[base + d] = f2bf(qf - bf2f(qh));
    float kf = kv[d] * ik;
    unsigned short kh = f2bf(kf);
    k_hi[base + d] = kh;
    k_lo[base + d] = f2bf(kf - bf2f(kh));
  }
}

// ---------------- K3: fused QK^T (split-bf16) -> exact top-512 -> softmax -> PV ----------------
// 16 waves, QT=16 rows; wave w owns row w. 65.8 KB LDS -> 2 WGs/CU (32 waves/CU).
__global__ __launch_bounds__(1024, 8) void k_attn(const unsigned short* __restrict__ q_hi,
                                                  const unsigned short* __restrict__ q_lo,
                                                  const unsigned short* __restrict__ k_hi,
                                                  const unsigned short* __restrict__ k_lo,
                                                  const unsigned short* __restrict__ vt,
                                                  unsigned short* __restrict__ ao) {
  extern __shared__ float smem[];
  float* sc = smem;                           // [16][HSTR] fp32 half-scores
  unsigned short* P = (unsigned short*)smem;  // [16][PSTH] bf16 half-P (aliases sc), XOR-swizzled
  float* red = smem;                          // flat partials (alias after P dead)
  int bid = blockIdx.x;
  int tile = bid & 127;                       // S/QT tiles per (b,h)
  int bh = bid >> 7;
  int q0 = tile * QT;
  int tid = threadIdx.x, lane = tid & 63, wv = tid >> 6;  // wv 0..15
  int l15 = lane & 15, lh = lane >> 4;
  const unsigned short* vb = vt + (size_t)bh * 32 * S_;

  // Q fragment: 16 distinct rows (no duplication)
  size_t qoff = ((size_t)bh * S_ + q0 + l15) * 32 + lh * 8;
  short8 ah = *(const short8*)(q_hi + qoff);
  short8 al = *(const short8*)(q_lo + qoff);
  size_t kbase = (size_t)bh * S_ * 32;

  float v[32];

  // ---- score halves: compute 16x1024 into sc, then waves pull their row to regs ----
#pragma unroll
  for (int hhalf = 0; hhalf < 2; ++hhalf) {
    int colbase = wv * 64;                    // this wave's 64-col span within the half
    const unsigned short* khp = k_hi + kbase + (size_t)(hhalf * HCOLS + colbase + l15) * 32 + lh * 8;
    const unsigned short* klp = k_lo + kbase + (size_t)(hhalf * HCOLS + colbase + l15) * 32 + lh * 8;
    short8 kh0 = *(const short8*)(khp);
    short8 kl0 = *(const short8*)(klp);
    short8 kh1 = *(const short8*)(khp + 512);
    short8 kl1 = *(const short8*)(klp + 512);
    for (int nt = 0; nt < 4; ++nt) {
      short8 kh2 = kh1, kl2 = kl1;
      if (nt < 2) {
        kh2 = *(const short8*)(khp + (nt + 2) * 512);
        kl2 = *(const short8*)(klp + (nt + 2) * 512);
      }
      f32x4 d = {};
      d = __builtin_amdgcn_mfma_f32_16x16x32_bf16(ah, kh0, d, 0, 0, 0);
      d = __builtin_amdgcn_mfma_f32_16x16x32_bf16(ah, kl0, d, 0, 0, 0);
      d = __builtin_amdgcn_mfma_f32_16x16x32_bf16(al, kh0, d, 0, 0, 0);
      int tloc = colbase + nt * 16;
#pragma unroll
      for (int r = 0; r < 4; ++r)
        sc[(lh * 4 + r) * HSTR + tloc + l15] = d[r];
      kh0 = kh1; kl0 = kl1; kh1 = kh2; kl1 = kl2;
    }
    __syncthreads();  // half scores complete
#pragma unroll
    for (int j = 0; j < 16; ++j)
      v[hhalf * 16 + j] = sc[wv * HSTR + lane + 64 * j];
    __syncthreads();  // all reads done; buffer reusable
  }

  // ---- selection (exact top-512) + softmax, all in registers ----
  // global col of v[j]: t = (j>>4)*1024 + (j&15)*64 + lane  (ascending in j, then lane)
  float vmax, ssum_is;
  {
    vmax = v[0];
    float vmin = v[0], sum = 0.f, sqs = 0.f;
#pragma unroll
    for (int j = 0; j < 32; ++j) {
      vmax = fmaxf(vmax, v[j]); vmin = fminf(vmin, v[j]);
      sum += v[j]; sqs = fmaf(v[j], v[j], sqs);
    }
#pragma unroll
    for (int m = 1; m < 64; m <<= 1) {
      vmax = fmaxf(vmax, __shfl_xor(vmax, m));
      vmin = fminf(vmin, __shfl_xor(vmin, m));
      sum += __shfl_xor(sum, m);
      sqs += __shfl_xor(sqs, m);
    }
    float mu = sum * (1.f / 2048.f);
    float sig = sqrtf(fmaxf(sqs * (1.f / 2048.f) - mu * mu, 0.f));

    // Illinois false position, initial pivot from Gaussian quantile (count 512/2048 -> z=0.6745)
    float vlo = vmin - 1e-3f, vhi = vmax;
    float flo = 1536.f, fhi = -512.f;
    int chi = 0;
    float T = vhi;
    bool exact = false;
    int lastside = 0;
    float piv = mu + 0.67449f * sig;
    if (!(piv > vlo && piv < vhi)) piv = 0.5f * (vlo + vhi);
    for (int it = 0; it < 32; ++it) {
      int c = 0;
#pragma unroll
      for (int j = 0; j < 32; ++j)
        c += (int)__popcll(__ballot(v[j] > piv));
      if (c == TOPK) { T = piv; exact = true; break; }
      if (c > TOPK) {
        if (lastside == 1) fhi *= 0.5f;
        vlo = piv; flo = (float)(c - TOPK); lastside = 1;
      } else {
        if (lastside == -1) flo *= 0.5f;
        vhi = piv; fhi = (float)(c - TOPK); chi = c; lastside = -1;
      }
      piv = vhi - fhi * (vhi - vlo) / (fhi - flo);
      if (!(piv > vlo && piv < vhi)) piv = 0.5f * (vlo + vhi);
      if (!(piv > vlo && piv < vhi)) break;  // interval collapsed (ties)
    }
    int cntGT = exact ? TOPK : chi;
    if (!exact) T = vhi;

    unsigned selbits = 0;
#pragma unroll
    for (int j = 0; j < 32; ++j)
      if (v[j] > T) selbits |= (1u << j);
    int need = TOPK - cntGT;
    if (need > 0) {
      // ties broken by lowest col index (jax top_k order); scan ascending t
      int base = 0;
      unsigned long long lmask = (lane == 0) ? 0ull : (~0ull >> (64 - lane));
#pragma unroll
      for (int j = 0; j < 32; ++j) {
        bool tie = (v[j] == T);
        unsigned long long m = __ballot(tie);
        int rank = base + (int)__popcll(m & lmask);
        if (tie && rank < need) selbits |= (1u << j);
        base += (int)__popcll(m);
      }
    }

    float ssum = 0.f;
#pragma unroll
    for (int j = 0; j < 32; ++j) {
      float e = ((selbits >> j) & 1u) ? __expf(v[j] - vmax) : 0.f;
      v[j] = e;
      ssum += e;
    }
#pragma unroll
    for (int m = 1; m < 64; m <<= 1) ssum += __shfl_xor(ssum, m);
    ssum_is = 1.f / ssum;
  }

  // ---- P write + PV per half; acc accumulates across halves ----
  // Swizzle: flat = (row*1024 + col) ^ (8*(row&7)); rows are 2048B-aligned and the XOR
  // only permutes 16B granules within each 128B block -> bijective per row (no cross-row
  // collisions, unlike the PSTH=1032 variant).
  f32x4 acc0 = {}, acc1 = {};
  int swz_w = (wv & 7) << 3;   // write swizzle (row = wv), ushort units
  int swz_r = (l15 & 7) << 3;  // read swizzle (row = l15)
#pragma unroll
  for (int hhalf = 0; hhalf < 2; ++hhalf) {
    // write this wave's row for cols [hhalf*1024, hhalf*1024+1024)
#pragma unroll
    for (int j = 0; j < 16; ++j) {
      int jj = hhalf * 16 + j;
      int idx = (wv * PSTH + j * 64 + lane) ^ swz_w;
      P[idx] = f2bf(v[jj] * ssum_is);
    }
    __syncthreads();  // half-P complete
    {
      const unsigned short* v0p = vb + (size_t)l15 * S_ + hhalf * HCOLS + wv * 64 + lh * 8;
      const unsigned short* v1p = v0p + 16 * S_;
#pragma unroll
      for (int kt = 0; kt < 2; ++kt) {
        int lc = wv * 64 + kt * 32 + lh * 8;
        int pidx = (l15 * PSTH + lc) ^ swz_r;
        short8 a = *(const short8*)(P + pidx);
        short8 b0 = *(const short8*)(v0p + kt * 32);
        short8 b1 = *(const short8*)(v1p + kt * 32);
        acc0 = __builtin_amdgcn_mfma_f32_16x16x32_bf16(a, b0, acc0, 0, 0, 0);
        acc1 = __builtin_amdgcn_mfma_f32_16x16x32_bf16(a, b1, acc1, 0, 0, 0);
      }
    }
    __syncthreads();  // PV reads done; buffer reusable
  }

  // ---- cross-wave reduction of 16 partial out(16x32) tiles ----
#pragma unroll
  for (int r = 0; r < 4; ++r) {
    red[wv * 529 + (lh * 4 + r) * 33 + l15] = acc0[r];
    red[wv * 529 + (lh * 4 + r) * 33 + 16 + l15] = acc1[r];
  }
  __syncthreads();
  if (tid < 512) {
    int row = tid >> 5, d = tid & 31;
    float s = 0.f;
#pragma unroll
    for (int w = 0; w < 16; ++w) s += red[w * 529 + row * 33 + d];
    ao[((size_t)bh * S_ + q0 + row) * 32 + d] = f2bf(s);
  }
}

// ---------------- K4: output projection ----------------
__global__ __launch_bounds__(256) void k_proj(const unsigned short* __restrict__ wbf,
                                              const unsigned short* __restrict__ ao,
                                              float* __restrict__ out) {
  int b = blockIdx.z;
  int m0 = blockIdx.y * 64, n0 = blockIdx.x * 64;
  int tid = threadIdx.x, lane = tid & 63, wid = tid >> 6;
  int l15 = lane & 15, lh = lane >> 4;
  int wm = (wid >> 1) * 32, wn = (wid & 1) * 32;
  const unsigned short* aob = ao + (size_t)b * H_ * S_ * 32;
  f32x4 acc[2][2] = {};
  int mA = m0 + wm + l15;
  int nB = n0 + wn + l15;
  for (int k0 = 0; k0 < C_; k0 += 32) {
    int kk = k0 + lh * 8;
    int hh = kk >> 5;
    int dd = kk & 31;
    short8 a0 = *(const short8*)(wbf + (size_t)mA * C_ + kk);
    short8 a1 = *(const short8*)(wbf + (size_t)(mA + 16) * C_ + kk);
    short8 b0 = *(const short8*)(aob + ((size_t)hh * S_ + nB) * 32 + dd);
    short8 b1 = *(const short8*)(aob + ((size_t)hh * S_ + nB + 16) * 32 + dd);
    acc[0][0] = __builtin_amdgcn_mfma_f32_16x16x32_bf16(a0, b0, acc[0][0], 0, 0, 0);
    acc[0][1] = __builtin_amdgcn_mfma_f32_16x16x32_bf16(a0, b1, acc[0][1], 0, 0, 0);
    acc[1][0] = __builtin_amdgcn_mfma_f32_16x16x32_bf16(a1, b0, acc[1][0], 0, 0, 0);
    acc[1][1] = __builtin_amdgcn_mfma_f32_16x16x32_bf16(a1, b1, acc[1][1], 0, 0, 0);
  }
  float* ob = out + (size_t)b * C_ * S_;
#pragma unroll
  for (int i = 0; i < 2; ++i)
#pragma unroll
    for (int j = 0; j < 2; ++j)
#pragma unroll
      for (int r = 0; r < 4; ++r) {
        int row = m0 + wm + i * 16 + lh * 4 + r;
        int col = n0 + wn + j * 16 + l15;
        ob[(size_t)row * S_ + col] = acc[i][j][r];
      }
}

extern "C" void kernel_launch(void* const* d_in, const int* in_sizes, int n_in,
                              void* d_out, int out_size, void* d_ws, size_t ws_size,
                              hipStream_t stream) {
  const float* x = (const float*)d_in[0];
  const float* wqkv = (const float*)d_in[1];
  const float* wdw = (const float*)d_in[2];
  const float* wproj = (const float*)d_in[3];
  const float* temp = (const float*)d_in[4];
  float* out = (float*)d_out;

  char* ws = (char*)d_ws;
  size_t off = 0;
  auto alloc = [&](size_t bytes) -> void* {
    void* p = ws + off;
    off += (bytes + 255) & ~(size_t)255;
    return p;
  };
  unsigned short* x_hi     = (unsigned short*)alloc((size_t)B_ * S_ * C_ * 2);
  unsigned short* x_lo     = (unsigned short*)alloc((size_t)B_ * S_ * C_ * 2);
  unsigned short* wq_hi    = (unsigned short*)alloc((size_t)O3_ * C_ * 2);
  unsigned short* wq_lo    = (unsigned short*)alloc((size_t)O3_ * C_ * 2);
  unsigned short* wproj_bf = (unsigned short*)alloc((size_t)C_ * C_ * 2);
  float*          raw      = (float*)alloc((size_t)B_ * O3_ * S_ * 4);
  unsigned short* k_hi     = (unsigned short*)alloc((size_t)B_ * H_ * S_ * 32 * 2);
  unsigned short* k_lo     = (unsigned short*)alloc((size_t)B_ * H_ * S_ * 32 * 2);
  unsigned short* vt       = (unsigned short*)alloc((size_t)B_ * H_ * 32 * S_ * 2);
  unsigned short* q_hi     = x_hi;                 // alias (x dead after k_qkv)
  unsigned short* q_lo     = x_lo;                 // alias
  unsigned short* ao       = (unsigned short*)raw; // alias (raw dead after k_dwnorm)

  (void)hipFuncSetAttribute(reinterpret_cast<const void*>(k_attn),
                            hipFuncAttributeMaxDynamicSharedMemorySize, (int)K3_LDS_BYTES);

  k_convw<<<dim3((O3_ * C_ + 255) / 256), dim3(256), 0, stream>>>(wqkv, wproj, wq_hi, wq_lo, wproj_bf);
  k_xt<<<dim3(S_ / 32, C_ / 32, B_), dim3(32, 8), 0, stream>>>(x, x_hi, x_lo);
  k_qkv<<<dim3(S_ / 64, O3_ / 64, B_), dim3(256), 0, stream>>>(wq_hi, wq_lo, x_hi, x_lo, raw);
  k_dwnorm<<<dim3(S_ / 256, H_, B_), dim3(256), 0, stream>>>(raw, wdw, temp, q_hi, q_lo, k_hi, k_lo, vt);
  k_attn<<<dim3(B_ * H_ * (S_ / QT)), dim3(1024), K3_LDS_BYTES, stream>>>(q_hi, q_lo, k_hi, k_lo, vt, ao);
  k_proj<<<dim3(S_ / 64, C_ / 64, B_), dim3(256), 0, stream>>>(wproj_bf, ao, out);
}

// Round 8
// 290.755 us; speedup vs baseline: 2.2291x; 1.0087x over previous
//
#include <hip/hip_runtime.h>
#include <math.h>

typedef __attribute__((ext_vector_type(8))) short short8;
typedef __attribute__((ext_vector_type(4))) float f32x4;
typedef __attribute__((ext_vector_type(2))) unsigned int uint2v;

#define DEV __device__ __forceinline__

static constexpr int B_ = 4, C_ = 256, S_ = 2048, H_ = 8, O3_ = 768;
static constexpr int TOPK = 512;
static constexpr int QT = 16;           // q rows per workgroup in attention
static constexpr int HCOLS = 1024;      // score cols staged per pass
static constexpr int HSTR = 1028;       // fp32 score row stride (half buffer)
static constexpr int PSTH = 1024;       // bf16 P half row stride; rows 2048B-aligned -> XOR swizzle bijective
static constexpr size_t K3_LDS_BYTES = (size_t)QT * HSTR * 4;  // 65792 B dynamic (+64B static) -> 2 WGs/CU

DEV unsigned cvt_pk_bf16(float a, float b) {
  unsigned r;
  asm("v_cvt_pk_bf16_f32 %0, %1, %2" : "=v"(r) : "v"(a), "v"(b));
  return r;  // lo16 = bf16(a), hi16 = bf16(b)
}
DEV unsigned short f2bf1(float f) { return (unsigned short)(cvt_pk_bf16(f, f) & 0xFFFFu); }
DEV float bf2f(unsigned short h) { return __uint_as_float(((unsigned)h) << 16); }
// hi/lo split: hi = bf16(f), lo = bf16(f - hi)
DEV void hilo(float f, unsigned short& h, unsigned short& l) {
  unsigned p = cvt_pk_bf16(f, f);
  h = (unsigned short)p;
  float r = f - __uint_as_float(p << 16);
  l = (unsigned short)(cvt_pk_bf16(r, r) & 0xFFFFu);
}

// ---------------- K0a: weights -> bf16 hi/lo (qkv), bf16 (proj) ----------------
__global__ void k_convw(const float* __restrict__ wqkv, const float* __restrict__ wproj,
                        unsigned short* __restrict__ wq_hi, unsigned short* __restrict__ wq_lo,
                        unsigned short* __restrict__ wproj_bf) {
  int i = blockIdx.x * 256 + threadIdx.x;
  if (i < O3_ * C_) {
    unsigned short h, l;
    hilo(wqkv[i], h, l);
    wq_hi[i] = h;
    wq_lo[i] = l;
  }
  if (i < C_ * C_) wproj_bf[i] = f2bf1(wproj[i]);
}

// ---------------- K0b: transpose x [b][c][s] -> xT hi/lo bf16 [b][s][c] ----------------
__global__ void k_xt(const float* __restrict__ x, unsigned short* __restrict__ xT_hi,
                     unsigned short* __restrict__ xT_lo) {
  __shared__ float t[32][33];
  int b = blockIdx.z;
  int c0 = blockIdx.y * 32, s0 = blockIdx.x * 32;
  int tx = threadIdx.x, ty = threadIdx.y;
  const float* xb = x + (size_t)b * C_ * S_;
#pragma unroll
  for (int j = 0; j < 4; ++j)
    t[ty + 8 * j][tx] = xb[(size_t)(c0 + ty + 8 * j) * S_ + s0 + tx];
  __syncthreads();
  unsigned short* hb = xT_hi + (size_t)b * S_ * C_;
  unsigned short* lb = xT_lo + (size_t)b * S_ * C_;
#pragma unroll
  for (int j = 0; j < 4; ++j) {
    unsigned short h, l;
    hilo(t[tx][ty + 8 * j], h, l);
    size_t o = (size_t)(s0 + ty + 8 * j) * C_ + c0 + tx;
    hb[o] = h;
    lb[o] = l;
  }
}

// ---------------- K1: qkv_raw = W_qkv @ x  (split-bf16 3-pass MFMA, ~fp32 accurate) ----------------
__global__ __launch_bounds__(256) void k_qkv(const unsigned short* __restrict__ w_hi,
                                             const unsigned short* __restrict__ w_lo,
                                             const unsigned short* __restrict__ x_hi,
                                             const unsigned short* __restrict__ x_lo,
                                             float* __restrict__ raw) {
  int b = blockIdx.z;
  int m0 = blockIdx.y * 64, n0 = blockIdx.x * 64;
  int tid = threadIdx.x, lane = tid & 63, wid = tid >> 6;
  int l15 = lane & 15, lh = lane >> 4;
  int wm = (wid >> 1) * 32, wn = (wid & 1) * 32;
  const unsigned short* xhb = x_hi + (size_t)b * S_ * C_;
  const unsigned short* xlb = x_lo + (size_t)b * S_ * C_;
  f32x4 acc[2][2] = {};
  int mA = m0 + wm + l15;
  int nB = n0 + wn + l15;
  for (int k0 = 0; k0 < C_; k0 += 32) {
    int kk = k0 + lh * 8;
    short8 a0h = *(const short8*)(w_hi + (size_t)mA * C_ + kk);
    short8 a1h = *(const short8*)(w_hi + (size_t)(mA + 16) * C_ + kk);
    short8 a0l = *(const short8*)(w_lo + (size_t)mA * C_ + kk);
    short8 a1l = *(const short8*)(w_lo + (size_t)(mA + 16) * C_ + kk);
    short8 b0h = *(const short8*)(xhb + (size_t)nB * C_ + kk);
    short8 b1h = *(const short8*)(xhb + (size_t)(nB + 16) * C_ + kk);
    short8 b0l = *(const short8*)(xlb + (size_t)nB * C_ + kk);
    short8 b1l = *(const short8*)(xlb + (size_t)(nB + 16) * C_ + kk);
    acc[0][0] = __builtin_amdgcn_mfma_f32_16x16x32_bf16(a0h, b0h, acc[0][0], 0, 0, 0);
    acc[0][1] = __builtin_amdgcn_mfma_f32_16x16x32_bf16(a0h, b1h, acc[0][1], 0, 0, 0);
    acc[1][0] = __builtin_amdgcn_mfma_f32_16x16x32_bf16(a1h, b0h, acc[1][0], 0, 0, 0);
    acc[1][1] = __builtin_amdgcn_mfma_f32_16x16x32_bf16(a1h, b1h, acc[1][1], 0, 0, 0);
    acc[0][0] = __builtin_amdgcn_mfma_f32_16x16x32_bf16(a0h, b0l, acc[0][0], 0, 0, 0);
    acc[0][1] = __builtin_amdgcn_mfma_f32_16x16x32_bf16(a0h, b1l, acc[0][1], 0, 0, 0);
    acc[1][0] = __builtin_amdgcn_mfma_f32_16x16x32_bf16(a1h, b0l, acc[1][0], 0, 0, 0);
    acc[1][1] = __builtin_amdgcn_mfma_f32_16x16x32_bf16(a1h, b1l, acc[1][1], 0, 0, 0);
    acc[0][0] = __builtin_amdgcn_mfma_f32_16x16x32_bf16(a0l, b0h, acc[0][0], 0, 0, 0);
    acc[0][1] = __builtin_amdgcn_mfma_f32_16x16x32_bf16(a0l, b1h, acc[0][1], 0, 0, 0);
    acc[1][0] = __builtin_amdgcn_mfma_f32_16x16x32_bf16(a1l, b0h, acc[1][0], 0, 0, 0);
    acc[1][1] = __builtin_amdgcn_mfma_f32_16x16x32_bf16(a1l, b1h, acc[1][1], 0, 0, 0);
  }
  float* rawb = raw + (size_t)b * O3_ * S_;
#pragma unroll
  for (int i = 0; i < 2; ++i)
#pragma unroll
    for (int j = 0; j < 2; ++j)
#pragma unroll
      for (int r = 0; r < 4; ++r) {
        int row = m0 + wm + i * 16 + lh * 4 + r;
        int col = n0 + wn + j * 16 + l15;
        rawb[(size_t)row * S_ + col] = acc[i][j][r];
      }
}

// ---------------- K2: depthwise conv + head split + l2norm (+temperature fold) ----------------
// d-split: lane = s_local*8 + d_group; each thread does 4 d's; norms via shfl_xor 1/2/4.
DEV float conv3(const float* __restrict__ rp, const float* __restrict__ w, int s) {
  float a = (s > 0) ? rp[s - 1] : 0.f;
  float b = rp[s];
  float c = (s < S_ - 1) ? rp[s + 1] : 0.f;
  return w[0] * a + w[1] * b + w[2] * c;
}

__global__ __launch_bounds__(256) void k_dwnorm(const float* __restrict__ raw,
                                                const float* __restrict__ wdw,
                                                const float* __restrict__ temp,
                                                unsigned short* __restrict__ q_hi,
                                                unsigned short* __restrict__ q_lo,
                                                unsigned short* __restrict__ k_hi,
                                                unsigned short* __restrict__ k_lo,
                                                unsigned short* __restrict__ vt) {
  int b = blockIdx.z, h = blockIdx.y;
  int tid = threadIdx.x;
  int wave = tid >> 6, lane = tid & 63;
  int dg = lane & 7;        // d-group (4 d's each)
  int sl = lane >> 3;       // s within wave
  int s = blockIdx.x * 32 + wave * 8 + sl;
  const float* rawb = raw + (size_t)b * O3_ * S_;
  float tph = temp[h];
  size_t bh = (size_t)(b * H_ + h);
  float qv[4], kv[4], vv[4];
  float sq = 0.f, sk = 0.f;
#pragma unroll
  for (int dd = 0; dd < 4; ++dd) {
    int d = dg * 4 + dd;
    int oq = h * 32 + d;
    float q = conv3(rawb + (size_t)oq * S_, wdw + oq * 3, s);
    qv[dd] = q; sq += q * q;
    int ok = oq + 256;
    float k = conv3(rawb + (size_t)ok * S_, wdw + ok * 3, s);
    kv[dd] = k; sk += k * k;
    int ov = oq + 512;
    vv[dd] = conv3(rawb + (size_t)ov * S_, wdw + ov * 3, s);
  }
#pragma unroll
  for (int m = 1; m < 8; m <<= 1) {
    sq += __shfl_xor(sq, m);
    sk += __shfl_xor(sk, m);
  }
  float iq = tph / fmaxf(sqrtf(sq), 1e-12f);
  float ik = 1.f / fmaxf(sqrtf(sk), 1e-12f);
  size_t base = (bh * S_ + s) * 32 + dg * 4;

  float q0 = qv[0] * iq, q1 = qv[1] * iq, q2 = qv[2] * iq, q3 = qv[3] * iq;
  unsigned qh01 = cvt_pk_bf16(q0, q1), qh23 = cvt_pk_bf16(q2, q3);
  *(uint2v*)(q_hi + base) = uint2v{qh01, qh23};
  float ql0 = q0 - __uint_as_float(qh01 << 16);
  float ql1 = q1 - __uint_as_float(qh01 & 0xFFFF0000u);
  float ql2 = q2 - __uint_as_float(qh23 << 16);
  float ql3 = q3 - __uint_as_float(qh23 & 0xFFFF0000u);
  *(uint2v*)(q_lo + base) = uint2v{cvt_pk_bf16(ql0, ql1), cvt_pk_bf16(ql2, ql3)};

  float k0 = kv[0] * ik, k1 = kv[1] * ik, k2 = kv[2] * ik, k3 = kv[3] * ik;
  unsigned kh01 = cvt_pk_bf16(k0, k1), kh23 = cvt_pk_bf16(k2, k3);
  *(uint2v*)(k_hi + base) = uint2v{kh01, kh23};
  float kl0 = k0 - __uint_as_float(kh01 << 16);
  float kl1 = k1 - __uint_as_float(kh01 & 0xFFFF0000u);
  float kl2 = k2 - __uint_as_float(kh23 << 16);
  float kl3 = k3 - __uint_as_float(kh23 & 0xFFFF0000u);
  *(uint2v*)(k_lo + base) = uint2v{cvt_pk_bf16(kl0, kl1), cvt_pk_bf16(kl2, kl3)};

#pragma unroll
  for (int dd = 0; dd < 4; ++dd) {
    int d = dg * 4 + dd;
    vt[(bh * 32 + d) * S_ + s] = f2bf1(vv[dd]);
  }
}

// ---------------- K3: fused QK^T (split-bf16) -> exact top-512 -> softmax -> PV ----------------
// 16 waves, QT=16 rows; wave w owns row w. 65.8 KB LDS -> 2 WGs/CU (32 waves/CU).
__global__ __launch_bounds__(1024, 8) void k_attn(const unsigned short* __restrict__ q_hi,
                                                  const unsigned short* __restrict__ q_lo,
                                                  const unsigned short* __restrict__ k_hi,
                                                  const unsigned short* __restrict__ k_lo,
                                                  const unsigned short* __restrict__ vt,
                                                  unsigned short* __restrict__ ao) {
  extern __shared__ float smem[];
  __shared__ float is_arr[QT];                // per-row 1/ssum (deferred normalization)
  float* sc = smem;                           // [16][HSTR] fp32 half-scores
  unsigned short* P = (unsigned short*)smem;  // [16][PSTH] bf16 half-P (aliases sc), XOR-swizzled
  float* red = smem;                          // flat partials (alias after P dead)
  int bid = blockIdx.x;
  int tile = bid & 127;                       // S/QT tiles per (b,h)
  int bh = bid >> 7;
  int q0 = tile * QT;
  int tid = threadIdx.x, lane = tid & 63, wv = tid >> 6;  // wv 0..15
  int l15 = lane & 15, lh = lane >> 4;
  const unsigned short* vb = vt + (size_t)bh * 32 * S_;

  // Q fragment: 16 distinct rows
  size_t qoff = ((size_t)bh * S_ + q0 + l15) * 32 + lh * 8;
  short8 ah = *(const short8*)(q_hi + qoff);
  short8 al = *(const short8*)(q_lo + qoff);
  size_t kbase = (size_t)bh * S_ * 32;

  float v[32];

  // ---- score halves: compute 16x1024 into sc, then waves pull their row to regs ----
#pragma unroll
  for (int hhalf = 0; hhalf < 2; ++hhalf) {
    int colbase = wv * 64;
    const unsigned short* khp = k_hi + kbase + (size_t)(hhalf * HCOLS + colbase + l15) * 32 + lh * 8;
    const unsigned short* klp = k_lo + kbase + (size_t)(hhalf * HCOLS + colbase + l15) * 32 + lh * 8;
    short8 kh0 = *(const short8*)(khp);
    short8 kl0 = *(const short8*)(klp);
    short8 kh1 = *(const short8*)(khp + 512);
    short8 kl1 = *(const short8*)(klp + 512);
    for (int nt = 0; nt < 4; ++nt) {
      short8 kh2 = kh1, kl2 = kl1;
      if (nt < 2) {
        kh2 = *(const short8*)(khp + (nt + 2) * 512);
        kl2 = *(const short8*)(klp + (nt + 2) * 512);
      }
      f32x4 d = {};
      d = __builtin_amdgcn_mfma_f32_16x16x32_bf16(ah, kh0, d, 0, 0, 0);
      d = __builtin_amdgcn_mfma_f32_16x16x32_bf16(ah, kl0, d, 0, 0, 0);
      d = __builtin_amdgcn_mfma_f32_16x16x32_bf16(al, kh0, d, 0, 0, 0);
      int tloc = colbase + nt * 16;
#pragma unroll
      for (int r = 0; r < 4; ++r)
        sc[(lh * 4 + r) * HSTR + tloc + l15] = d[r];
      kh0 = kh1; kl0 = kl1; kh1 = kh2; kl1 = kl2;
    }
    __syncthreads();
#pragma unroll
    for (int j = 0; j < 16; ++j)
      v[hhalf * 16 + j] = sc[wv * HSTR + lane + 64 * j];
    __syncthreads();
  }

  // ---- selection (exact top-512) + softmax weights, all in registers ----
  // global col of v[j]: t = (j>>4)*1024 + (j&15)*64 + lane
  float vmax;
  {
    vmax = v[0];
    float vmin = v[0], sum = 0.f, sqs = 0.f;
#pragma unroll
    for (int j = 0; j < 32; ++j) {
      vmax = fmaxf(vmax, v[j]); vmin = fminf(vmin, v[j]);
      sum += v[j]; sqs = fmaf(v[j], v[j], sqs);
    }
#pragma unroll
    for (int m = 1; m < 64; m <<= 1) {
      vmax = fmaxf(vmax, __shfl_xor(vmax, m));
      vmin = fminf(vmin, __shfl_xor(vmin, m));
      sum += __shfl_xor(sum, m);
      sqs += __shfl_xor(sqs, m);
    }
    float mu = sum * (1.f / 2048.f);
    float sig = sqrtf(fmaxf(sqs * (1.f / 2048.f) - mu * mu, 0.f));

    // Illinois false position; seed = Gaussian quantile; 2nd pivot = Newton w/ pdf slope.
    float vlo = vmin - 1e-3f, vhi = vmax;
    float flo = 1536.f, fhi = -512.f;
    int chi = 0;
    float T = vhi;
    bool exact = false;
    int lastside = 0;
    float piv = mu + 0.67449f * sig;
    if (!(piv > vlo && piv < vhi)) piv = 0.5f * (vlo + vhi);
    for (int it = 0; it < 32; ++it) {
      int c = 0;
#pragma unroll
      for (int j = 0; j < 32; ++j)
        c += (int)__popcll(__ballot(v[j] > piv));
      if (c == TOPK) { T = piv; exact = true; break; }
      if (c > TOPK) {
        if (lastside == 1) fhi *= 0.5f;
        vlo = piv; flo = (float)(c - TOPK); lastside = 1;
      } else {
        if (lastside == -1) flo *= 0.5f;
        vhi = piv; fhi = (float)(c - TOPK); chi = c; lastside = -1;
      }
      float npiv;
      if (it == 0 && sig > 1e-20f) {
        float z = (piv - mu) / sig;
        float dens = 0.398942f * __expf(-0.5f * z * z) * (2048.f / sig);  // -dC/dpiv
        npiv = piv + (float)(c - TOPK) / fmaxf(dens, 1e-6f);
      } else {
        npiv = vhi - fhi * (vhi - vlo) / (fhi - flo);
      }
      if (!(npiv > vlo && npiv < vhi)) npiv = 0.5f * (vlo + vhi);
      if (!(npiv > vlo && npiv < vhi)) break;  // interval collapsed (ties)
      piv = npiv;
    }
    int cntGT = exact ? TOPK : chi;
    if (!exact) T = vhi;

    unsigned selbits = 0;
#pragma unroll
    for (int j = 0; j < 32; ++j)
      if (v[j] > T) selbits |= (1u << j);
    int need = TOPK - cntGT;
    if (need > 0) {
      // ties broken by lowest col index (jax top_k order); scan ascending t
      int base = 0;
      unsigned long long lmask = (lane == 0) ? 0ull : (~0ull >> (64 - lane));
#pragma unroll
      for (int j = 0; j < 32; ++j) {
        bool tie = (v[j] == T);
        unsigned long long m = __ballot(tie);
        int rank = base + (int)__popcll(m & lmask);
        if (tie && rank < need) selbits |= (1u << j);
        base += (int)__popcll(m);
      }
    }

    float ssum = 0.f;
#pragma unroll
    for (int j = 0; j < 32; ++j) {
      float e = ((selbits >> j) & 1u) ? __expf(v[j] - vmax) : 0.f;
      v[j] = e;
      ssum += e;
    }
#pragma unroll
    for (int m = 1; m < 64; m <<= 1) ssum += __shfl_xor(ssum, m);
    if (lane == 0) is_arr[wv] = 1.f / ssum;   // visible after next barrier
  }

  // ---- P write (unnormalized exp) + PV per half; acc accumulates across halves ----
  // Swizzle: flat = (row*1024 + col) ^ (8*(row&7)) — bijective (rows 2048B-aligned).
  f32x4 acc0 = {}, acc1 = {};
  int swz_w = (wv & 7) << 3;
  int swz_r = (l15 & 7) << 3;
#pragma unroll
  for (int hhalf = 0; hhalf < 2; ++hhalf) {
    // prefetch V fragments for this half (independent of P) — in flight during P write + barrier
    const unsigned short* v0p = vb + (size_t)l15 * S_ + hhalf * HCOLS + wv * 64 + lh * 8;
    const unsigned short* v1p = v0p + 16 * S_;
    short8 b00 = *(const short8*)(v0p);
    short8 b10 = *(const short8*)(v1p);
    short8 b01 = *(const short8*)(v0p + 32);
    short8 b11 = *(const short8*)(v1p + 32);
#pragma unroll
    for (int j = 0; j < 16; ++j) {
      int idx = (wv * PSTH + j * 64 + lane) ^ swz_w;
      P[idx] = f2bf1(v[hhalf * 16 + j]);
    }
    __syncthreads();  // half-P complete
    {
      int lc0 = wv * 64 + lh * 8;
      short8 a0 = *(const short8*)(P + ((l15 * PSTH + lc0) ^ swz_r));
      short8 a1 = *(const short8*)(P + ((l15 * PSTH + lc0 + 32) ^ swz_r));
      acc0 = __builtin_amdgcn_mfma_f32_16x16x32_bf16(a0, b00, acc0, 0, 0, 0);
      acc1 = __builtin_amdgcn_mfma_f32_16x16x32_bf16(a0, b10, acc1, 0, 0, 0);
      acc0 = __builtin_amdgcn_mfma_f32_16x16x32_bf16(a1, b01, acc0, 0, 0, 0);
      acc1 = __builtin_amdgcn_mfma_f32_16x16x32_bf16(a1, b11, acc1, 0, 0, 0);
    }
    __syncthreads();  // PV reads done; buffer reusable
  }

  // ---- cross-wave reduction of 16 partial out(16x32) tiles ----
#pragma unroll
  for (int r = 0; r < 4; ++r) {
    red[wv * 529 + (lh * 4 + r) * 33 + l15] = acc0[r];
    red[wv * 529 + (lh * 4 + r) * 33 + 16 + l15] = acc1[r];
  }
  __syncthreads();
  if (tid < 512) {
    int row = tid >> 5, d = tid & 31;
    float s = 0.f;
#pragma unroll
    for (int w = 0; w < 16; ++w) s += red[w * 529 + row * 33 + d];
    s *= is_arr[row];
    ao[((size_t)bh * S_ + q0 + row) * 32 + d] = f2bf1(s);
  }
}

// ---------------- K4: output projection ----------------
__global__ __launch_bounds__(256) void k_proj(const unsigned short* __restrict__ wbf,
                                              const unsigned short* __restrict__ ao,
                                              float* __restrict__ out) {
  int b = blockIdx.z;
  int m0 = blockIdx.y * 64, n0 = blockIdx.x * 64;
  int tid = threadIdx.x, lane = tid & 63, wid = tid >> 6;
  int l15 = lane & 15, lh = lane >> 4;
  int wm = (wid >> 1) * 32, wn = (wid & 1) * 32;
  const unsigned short* aob = ao + (size_t)b * H_ * S_ * 32;
  f32x4 acc[2][2] = {};
  int mA = m0 + wm + l15;
  int nB = n0 + wn + l15;
  for (int k0 = 0; k0 < C_; k0 += 32) {
    int kk = k0 + lh * 8;
    int hh = kk >> 5;
    int dd = kk & 31;
    short8 a0 = *(const short8*)(wbf + (size_t)mA * C_ + kk);
    short8 a1 = *(const short8*)(wbf + (size_t)(mA + 16) * C_ + kk);
    short8 b0 = *(const short8*)(aob + ((size_t)hh * S_ + nB) * 32 + dd);
    short8 b1 = *(const short8*)(aob + ((size_t)hh * S_ + nB + 16) * 32 + dd);
    acc[0][0] = __builtin_amdgcn_mfma_f32_16x16x32_bf16(a0, b0, acc[0][0], 0, 0, 0);
    acc[0][1] = __builtin_amdgcn_mfma_f32_16x16x32_bf16(a0, b1, acc[0][1], 0, 0, 0);
    acc[1][0] = __builtin_amdgcn_mfma_f32_16x16x32_bf16(a1, b0, acc[1][0], 0, 0, 0);
    acc[1][1] = __builtin_amdgcn_mfma_f32_16x16x32_bf16(a1, b1, acc[1][1], 0, 0, 0);
  }
  float* ob = out + (size_t)b * C_ * S_;
#pragma unroll
  for (int i = 0; i < 2; ++i)
#pragma unroll
    for (int j = 0; j < 2; ++j)
#pragma unroll
      for (int r = 0; r < 4; ++r) {
        int row = m0 + wm + i * 16 + lh * 4 + r;
        int col = n0 + wn + j * 16 + l15;
        ob[(size_t)row * S_ + col] = acc[i][j][r];
      }
}

extern "C" void kernel_launch(void* const* d_in, const int* in_sizes, int n_in,
                              void* d_out, int out_size, void* d_ws, size_t ws_size,
                              hipStream_t stream) {
  const float* x = (const float*)d_in[0];
  const float* wqkv = (const float*)d_in[1];
  const float* wdw = (const float*)d_in[2];
  const float* wproj = (const float*)d_in[3];
  const float* temp = (const float*)d_in[4];
  float* out = (float*)d_out;

  char* ws = (char*)d_ws;
  size_t off = 0;
  auto alloc = [&](size_t bytes) -> void* {
    void* p = ws + off;
    off += (bytes + 255) & ~(size_t)255;
    return p;
  };
  unsigned short* x_hi     = (unsigned short*)alloc((size_t)B_ * S_ * C_ * 2);
  unsigned short* x_lo     = (unsigned short*)alloc((size_t)B_ * S_ * C_ * 2);
  unsigned short* wq_hi    = (unsigned short*)alloc((size_t)O3_ * C_ * 2);
  unsigned short* wq_lo    = (unsigned short*)alloc((size_t)O3_ * C_ * 2);
  unsigned short* wproj_bf = (unsigned short*)alloc((size_t)C_ * C_ * 2);
  float*          raw      = (float*)alloc((size_t)B_ * O3_ * S_ * 4);
  unsigned short* k_hi     = (unsigned short*)alloc((size_t)B_ * H_ * S_ * 32 * 2);
  unsigned short* k_lo     = (unsigned short*)alloc((size_t)B_ * H_ * S_ * 32 * 2);
  unsigned short* vt       = (unsigned short*)alloc((size_t)B_ * H_ * 32 * S_ * 2);
  unsigned short* q_hi     = x_hi;                 // alias (x dead after k_qkv)
  unsigned short* q_lo     = x_lo;                 // alias
  unsigned short* ao       = (unsigned short*)raw; // alias (raw dead after k_dwnorm)

  (void)hipFuncSetAttribute(reinterpret_cast<const void*>(k_attn),
                            hipFuncAttributeMaxDynamicSharedMemorySize, (int)K3_LDS_BYTES);

  k_convw<<<dim3((O3_ * C_ + 255) / 256), dim3(256), 0, stream>>>(wqkv, wproj, wq_hi, wq_lo, wproj_bf);
  k_xt<<<dim3(S_ / 32, C_ / 32, B_), dim3(32, 8), 0, stream>>>(x, x_hi, x_lo);
  k_qkv<<<dim3(S_ / 64, O3_ / 64, B_), dim3(256), 0, stream>>>(wq_hi, wq_lo, x_hi, x_lo, raw);
  k_dwnorm<<<dim3(S_ / 32, H_, B_), dim3(256), 0, stream>>>(raw, wdw, temp, q_hi, q_lo, k_hi, k_lo, vt);
  k_attn<<<dim3(B_ * H_ * (S_ / QT)), dim3(1024), K3_LDS_BYTES, stream>>>(q_hi, q_lo, k_hi, k_lo, vt, ao);
  k_proj<<<dim3(S_ / 64, C_ / 64, B_), dim3(256), 0, stream>>>(wproj_bf, ao, out);
}

// Round 9
// 289.260 us; speedup vs baseline: 2.2406x; 1.0052x over previous
//
#include <hip/hip_runtime.h>
#include <math.h>

typedef __attribute__((ext_vector_type(8))) short short8;
typedef __attribute__((ext_vector_type(4))) float f32x4;
typedef __attribute__((ext_vector_type(2))) unsigned int uint2v;

#define DEV __device__ __forceinline__

static constexpr int B_ = 4, C_ = 256, S_ = 2048, H_ = 8, O3_ = 768;
static constexpr int TOPK = 512;
static constexpr int QT = 16;           // q rows per workgroup in attention
static constexpr int HCOLS = 1024;      // score cols staged per pass
static constexpr int HSTR = 1028;       // fp32 score row stride (half buffer)
static constexpr int PSTH = 1024;       // bf16 P half row stride; rows 2048B-aligned -> XOR swizzle bijective
static constexpr size_t K3_LDS_BYTES = (size_t)QT * HSTR * 4;  // 65792 B dynamic (+64B static) -> 2 WGs/CU

DEV unsigned cvt_pk_bf16(float a, float b) {
  unsigned r;
  asm("v_cvt_pk_bf16_f32 %0, %1, %2" : "=v"(r) : "v"(a), "v"(b));
  return r;  // lo16 = bf16(a), hi16 = bf16(b)
}
DEV unsigned short f2bf1(float f) { return (unsigned short)(cvt_pk_bf16(f, f) & 0xFFFFu); }
DEV float bf2f(unsigned short h) { return __uint_as_float(((unsigned)h) << 16); }
// hi/lo split: hi = bf16(f), lo = bf16(f - hi)
DEV void hilo(float f, unsigned short& h, unsigned short& l) {
  unsigned p = cvt_pk_bf16(f, f);
  h = (unsigned short)p;
  float r = f - __uint_as_float(p << 16);
  l = (unsigned short)(cvt_pk_bf16(r, r) & 0xFFFFu);
}

// ---------------- K0a: weights -> bf16 hi/lo (qkv), bf16 (proj) ----------------
__global__ void k_convw(const float* __restrict__ wqkv, const float* __restrict__ wproj,
                        unsigned short* __restrict__ wq_hi, unsigned short* __restrict__ wq_lo,
                        unsigned short* __restrict__ wproj_bf) {
  int i = blockIdx.x * 256 + threadIdx.x;
  if (i < O3_ * C_) {
    unsigned short h, l;
    hilo(wqkv[i], h, l);
    wq_hi[i] = h;
    wq_lo[i] = l;
  }
  if (i < C_ * C_) wproj_bf[i] = f2bf1(wproj[i]);
}

// ---------------- K0b: transpose x [b][c][s] -> xT hi/lo bf16 [b][s][c] ----------------
__global__ void k_xt(const float* __restrict__ x, unsigned short* __restrict__ xT_hi,
                     unsigned short* __restrict__ xT_lo) {
  __shared__ float t[32][33];
  int b = blockIdx.z;
  int c0 = blockIdx.y * 32, s0 = blockIdx.x * 32;
  int tx = threadIdx.x, ty = threadIdx.y;
  const float* xb = x + (size_t)b * C_ * S_;
#pragma unroll
  for (int j = 0; j < 4; ++j)
    t[ty + 8 * j][tx] = xb[(size_t)(c0 + ty + 8 * j) * S_ + s0 + tx];
  __syncthreads();
  unsigned short* hb = xT_hi + (size_t)b * S_ * C_;
  unsigned short* lb = xT_lo + (size_t)b * S_ * C_;
#pragma unroll
  for (int j = 0; j < 4; ++j) {
    unsigned short h, l;
    hilo(t[tx][ty + 8 * j], h, l);
    size_t o = (size_t)(s0 + ty + 8 * j) * C_ + c0 + tx;
    hb[o] = h;
    lb[o] = l;
  }
}

// ---------------- K1: qkv_raw = W_qkv @ x  (split-bf16 3-pass MFMA, ~fp32 accurate) ----------------
__global__ __launch_bounds__(256) void k_qkv(const unsigned short* __restrict__ w_hi,
                                             const unsigned short* __restrict__ w_lo,
                                             const unsigned short* __restrict__ x_hi,
                                             const unsigned short* __restrict__ x_lo,
                                             float* __restrict__ raw) {
  int b = blockIdx.z;
  int m0 = blockIdx.y * 64, n0 = blockIdx.x * 64;
  int tid = threadIdx.x, lane = tid & 63, wid = tid >> 6;
  int l15 = lane & 15, lh = lane >> 4;
  int wm = (wid >> 1) * 32, wn = (wid & 1) * 32;
  const unsigned short* xhb = x_hi + (size_t)b * S_ * C_;
  const unsigned short* xlb = x_lo + (size_t)b * S_ * C_;
  f32x4 acc[2][2] = {};
  int mA = m0 + wm + l15;
  int nB = n0 + wn + l15;
  for (int k0 = 0; k0 < C_; k0 += 32) {
    int kk = k0 + lh * 8;
    short8 a0h = *(const short8*)(w_hi + (size_t)mA * C_ + kk);
    short8 a1h = *(const short8*)(w_hi + (size_t)(mA + 16) * C_ + kk);
    short8 a0l = *(const short8*)(w_lo + (size_t)mA * C_ + kk);
    short8 a1l = *(const short8*)(w_lo + (size_t)(mA + 16) * C_ + kk);
    short8 b0h = *(const short8*)(xhb + (size_t)nB * C_ + kk);
    short8 b1h = *(const short8*)(xhb + (size_t)(nB + 16) * C_ + kk);
    short8 b0l = *(const short8*)(xlb + (size_t)nB * C_ + kk);
    short8 b1l = *(const short8*)(xlb + (size_t)(nB + 16) * C_ + kk);
    acc[0][0] = __builtin_amdgcn_mfma_f32_16x16x32_bf16(a0h, b0h, acc[0][0], 0, 0, 0);
    acc[0][1] = __builtin_amdgcn_mfma_f32_16x16x32_bf16(a0h, b1h, acc[0][1], 0, 0, 0);
    acc[1][0] = __builtin_amdgcn_mfma_f32_16x16x32_bf16(a1h, b0h, acc[1][0], 0, 0, 0);
    acc[1][1] = __builtin_amdgcn_mfma_f32_16x16x32_bf16(a1h, b1h, acc[1][1], 0, 0, 0);
    acc[0][0] = __builtin_amdgcn_mfma_f32_16x16x32_bf16(a0h, b0l, acc[0][0], 0, 0, 0);
    acc[0][1] = __builtin_amdgcn_mfma_f32_16x16x32_bf16(a0h, b1l, acc[0][1], 0, 0, 0);
    acc[1][0] = __builtin_amdgcn_mfma_f32_16x16x32_bf16(a1h, b0l, acc[1][0], 0, 0, 0);
    acc[1][1] = __builtin_amdgcn_mfma_f32_16x16x32_bf16(a1h, b1l, acc[1][1], 0, 0, 0);
    acc[0][0] = __builtin_amdgcn_mfma_f32_16x16x32_bf16(a0l, b0h, acc[0][0], 0, 0, 0);
    acc[0][1] = __builtin_amdgcn_mfma_f32_16x16x32_bf16(a0l, b1h, acc[0][1], 0, 0, 0);
    acc[1][0] = __builtin_amdgcn_mfma_f32_16x16x32_bf16(a1l, b0h, acc[1][0], 0, 0, 0);
    acc[1][1] = __builtin_amdgcn_mfma_f32_16x16x32_bf16(a1l, b1h, acc[1][1], 0, 0, 0);
  }
  float* rawb = raw + (size_t)b * O3_ * S_;
#pragma unroll
  for (int i = 0; i < 2; ++i)
#pragma unroll
    for (int j = 0; j < 2; ++j)
#pragma unroll
      for (int r = 0; r < 4; ++r) {
        int row = m0 + wm + i * 16 + lh * 4 + r;
        int col = n0 + wn + j * 16 + l15;
        rawb[(size_t)row * S_ + col] = acc[i][j][r];
      }
}

// ---------------- K2: depthwise conv + head split + l2norm (+temperature fold) ----------------
DEV float conv3(const float* __restrict__ rp, const float* __restrict__ w, int s) {
  float a = (s > 0) ? rp[s - 1] : 0.f;
  float b = rp[s];
  float c = (s < S_ - 1) ? rp[s + 1] : 0.f;
  return w[0] * a + w[1] * b + w[2] * c;
}

__global__ __launch_bounds__(256) void k_dwnorm(const float* __restrict__ raw,
                                                const float* __restrict__ wdw,
                                                const float* __restrict__ temp,
                                                unsigned short* __restrict__ q_hi,
                                                unsigned short* __restrict__ q_lo,
                                                unsigned short* __restrict__ k_hi,
                                                unsigned short* __restrict__ k_lo,
                                                unsigned short* __restrict__ vt) {
  int b = blockIdx.z, h = blockIdx.y;
  int tid = threadIdx.x;
  int wave = tid >> 6, lane = tid & 63;
  int dg = lane & 7;        // d-group (4 d's each)
  int sl = lane >> 3;       // s within wave
  int s = blockIdx.x * 32 + wave * 8 + sl;
  const float* rawb = raw + (size_t)b * O3_ * S_;
  float tph = temp[h];
  size_t bh = (size_t)(b * H_ + h);
  float qv[4], kv[4], vv[4];
  float sq = 0.f, sk = 0.f;
#pragma unroll
  for (int dd = 0; dd < 4; ++dd) {
    int d = dg * 4 + dd;
    int oq = h * 32 + d;
    float q = conv3(rawb + (size_t)oq * S_, wdw + oq * 3, s);
    qv[dd] = q; sq += q * q;
    int ok = oq + 256;
    float k = conv3(rawb + (size_t)ok * S_, wdw + ok * 3, s);
    kv[dd] = k; sk += k * k;
    int ov = oq + 512;
    vv[dd] = conv3(rawb + (size_t)ov * S_, wdw + ov * 3, s);
  }
#pragma unroll
  for (int m = 1; m < 8; m <<= 1) {
    sq += __shfl_xor(sq, m);
    sk += __shfl_xor(sk, m);
  }
  float iq = tph / fmaxf(sqrtf(sq), 1e-12f);
  float ik = 1.f / fmaxf(sqrtf(sk), 1e-12f);
  size_t base = (bh * S_ + s) * 32 + dg * 4;

  float q0 = qv[0] * iq, q1 = qv[1] * iq, q2 = qv[2] * iq, q3 = qv[3] * iq;
  unsigned qh01 = cvt_pk_bf16(q0, q1), qh23 = cvt_pk_bf16(q2, q3);
  *(uint2v*)(q_hi + base) = uint2v{qh01, qh23};
  float ql0 = q0 - __uint_as_float(qh01 << 16);
  float ql1 = q1 - __uint_as_float(qh01 & 0xFFFF0000u);
  float ql2 = q2 - __uint_as_float(qh23 << 16);
  float ql3 = q3 - __uint_as_float(qh23 & 0xFFFF0000u);
  *(uint2v*)(q_lo + base) = uint2v{cvt_pk_bf16(ql0, ql1), cvt_pk_bf16(ql2, ql3)};

  float k0 = kv[0] * ik, k1 = kv[1] * ik, k2 = kv[2] * ik, k3 = kv[3] * ik;
  unsigned kh01 = cvt_pk_bf16(k0, k1), kh23 = cvt_pk_bf16(k2, k3);
  *(uint2v*)(k_hi + base) = uint2v{kh01, kh23};
  float kl0 = k0 - __uint_as_float(kh01 << 16);
  float kl1 = k1 - __uint_as_float(kh01 & 0xFFFF0000u);
  float kl2 = k2 - __uint_as_float(kh23 << 16);
  float kl3 = k3 - __uint_as_float(kh23 & 0xFFFF0000u);
  *(uint2v*)(k_lo + base) = uint2v{cvt_pk_bf16(kl0, kl1), cvt_pk_bf16(kl2, kl3)};

#pragma unroll
  for (int dd = 0; dd < 4; ++dd) {
    int d = dg * 4 + dd;
    vt[(bh * 32 + d) * S_ + s] = f2bf1(vv[dd]);
  }
}

// ---------------- K3: fused QK^T (split-bf16) -> exact top-512 -> softmax -> PV ----------------
// 16 waves, QT=16 rows; wave w owns row w. 65.8 KB LDS -> 2 WGs/CU (32 waves/CU).
// NOTE: V-fragment loads deliberately placed AFTER the P-write barrier (short live range).
// R8 held them across the P-write loop + barrier -> VGPR spill (WRITE_SIZE 4MB -> 281MB).
__global__ __launch_bounds__(1024, 8) void k_attn(const unsigned short* __restrict__ q_hi,
                                                  const unsigned short* __restrict__ q_lo,
                                                  const unsigned short* __restrict__ k_hi,
                                                  const unsigned short* __restrict__ k_lo,
                                                  const unsigned short* __restrict__ vt,
                                                  unsigned short* __restrict__ ao) {
  extern __shared__ float smem[];
  __shared__ float is_arr[QT];                // per-row 1/ssum (deferred normalization)
  float* sc = smem;                           // [16][HSTR] fp32 half-scores
  unsigned short* P = (unsigned short*)smem;  // [16][PSTH] bf16 half-P (aliases sc), XOR-swizzled
  float* red = smem;                          // flat partials (alias after P dead)
  int bid = blockIdx.x;
  int tile = bid & 127;                       // S/QT tiles per (b,h)
  int bh = bid >> 7;
  int q0 = tile * QT;
  int tid = threadIdx.x, lane = tid & 63, wv = tid >> 6;  // wv 0..15
  int l15 = lane & 15, lh = lane >> 4;
  const unsigned short* vb = vt + (size_t)bh * 32 * S_;

  // Q fragment: 16 distinct rows
  size_t qoff = ((size_t)bh * S_ + q0 + l15) * 32 + lh * 8;
  short8 ah = *(const short8*)(q_hi + qoff);
  short8 al = *(const short8*)(q_lo + qoff);
  size_t kbase = (size_t)bh * S_ * 32;

  float v[32];

  // ---- score halves: compute 16x1024 into sc, then waves pull their row to regs ----
#pragma unroll
  for (int hhalf = 0; hhalf < 2; ++hhalf) {
    int colbase = wv * 64;
    const unsigned short* khp = k_hi + kbase + (size_t)(hhalf * HCOLS + colbase + l15) * 32 + lh * 8;
    const unsigned short* klp = k_lo + kbase + (size_t)(hhalf * HCOLS + colbase + l15) * 32 + lh * 8;
    short8 kh0 = *(const short8*)(khp);
    short8 kl0 = *(const short8*)(klp);
    short8 kh1 = *(const short8*)(khp + 512);
    short8 kl1 = *(const short8*)(klp + 512);
    for (int nt = 0; nt < 4; ++nt) {
      short8 kh2 = kh1, kl2 = kl1;
      if (nt < 2) {
        kh2 = *(const short8*)(khp + (nt + 2) * 512);
        kl2 = *(const short8*)(klp + (nt + 2) * 512);
      }
      f32x4 d = {};
      d = __builtin_amdgcn_mfma_f32_16x16x32_bf16(ah, kh0, d, 0, 0, 0);
      d = __builtin_amdgcn_mfma_f32_16x16x32_bf16(ah, kl0, d, 0, 0, 0);
      d = __builtin_amdgcn_mfma_f32_16x16x32_bf16(al, kh0, d, 0, 0, 0);
      int tloc = colbase + nt * 16;
#pragma unroll
      for (int r = 0; r < 4; ++r)
        sc[(lh * 4 + r) * HSTR + tloc + l15] = d[r];
      kh0 = kh1; kl0 = kl1; kh1 = kh2; kl1 = kl2;
    }
    __syncthreads();
#pragma unroll
    for (int j = 0; j < 16; ++j)
      v[hhalf * 16 + j] = sc[wv * HSTR + lane + 64 * j];
    __syncthreads();
  }

  // ---- selection (exact top-512) + softmax weights, all in registers ----
  // global col of v[j]: t = (j>>4)*1024 + (j&15)*64 + lane
  float vmax;
  {
    vmax = v[0];
    float vmin = v[0], sum = 0.f, sqs = 0.f;
#pragma unroll
    for (int j = 0; j < 32; ++j) {
      vmax = fmaxf(vmax, v[j]); vmin = fminf(vmin, v[j]);
      sum += v[j]; sqs = fmaf(v[j], v[j], sqs);
    }
#pragma unroll
    for (int m = 1; m < 64; m <<= 1) {
      vmax = fmaxf(vmax, __shfl_xor(vmax, m));
      vmin = fminf(vmin, __shfl_xor(vmin, m));
      sum += __shfl_xor(sum, m);
      sqs += __shfl_xor(sqs, m);
    }
    float mu = sum * (1.f / 2048.f);
    float sig = sqrtf(fmaxf(sqs * (1.f / 2048.f) - mu * mu, 0.f));

    // Illinois false position; seed = Gaussian quantile; 2nd pivot = Newton w/ pdf slope.
    float vlo = vmin - 1e-3f, vhi = vmax;
    float flo = 1536.f, fhi = -512.f;
    int chi = 0;
    float T = vhi;
    bool exact = false;
    int lastside = 0;
    float piv = mu + 0.67449f * sig;
    if (!(piv > vlo && piv < vhi)) piv = 0.5f * (vlo + vhi);
    for (int it = 0; it < 32; ++it) {
      int c = 0;
#pragma unroll
      for (int j = 0; j < 32; ++j)
        c += (int)__popcll(__ballot(v[j] > piv));
      if (c == TOPK) { T = piv; exact = true; break; }
      if (c > TOPK) {
        if (lastside == 1) fhi *= 0.5f;
        vlo = piv; flo = (float)(c - TOPK); lastside = 1;
      } else {
        if (lastside == -1) flo *= 0.5f;
        vhi = piv; fhi = (float)(c - TOPK); chi = c; lastside = -1;
      }
      float npiv;
      if (it == 0 && sig > 1e-20f) {
        float z = (piv - mu) / sig;
        float dens = 0.398942f * __expf(-0.5f * z * z) * (2048.f / sig);  // -dC/dpiv
        npiv = piv + (float)(c - TOPK) / fmaxf(dens, 1e-6f);
      } else {
        npiv = vhi - fhi * (vhi - vlo) / (fhi - flo);
      }
      if (!(npiv > vlo && npiv < vhi)) npiv = 0.5f * (vlo + vhi);
      if (!(npiv > vlo && npiv < vhi)) break;  // interval collapsed (ties)
      piv = npiv;
    }
    int cntGT = exact ? TOPK : chi;
    if (!exact) T = vhi;

    unsigned selbits = 0;
#pragma unroll
    for (int j = 0; j < 32; ++j)
      if (v[j] > T) selbits |= (1u << j);
    int need = TOPK - cntGT;
    if (need > 0) {
      // ties broken by lowest col index (jax top_k order); scan ascending t
      int base = 0;
      unsigned long long lmask = (lane == 0) ? 0ull : (~0ull >> (64 - lane));
#pragma unroll
      for (int j = 0; j < 32; ++j) {
        bool tie = (v[j] == T);
        unsigned long long m = __ballot(tie);
        int rank = base + (int)__popcll(m & lmask);
        if (tie && rank < need) selbits |= (1u << j);
        base += (int)__popcll(m);
      }
    }

    float ssum = 0.f;
#pragma unroll
    for (int j = 0; j < 32; ++j) {
      float e = ((selbits >> j) & 1u) ? __expf(v[j] - vmax) : 0.f;
      v[j] = e;
      ssum += e;
    }
#pragma unroll
    for (int m = 1; m < 64; m <<= 1) ssum += __shfl_xor(ssum, m);
    if (lane == 0) is_arr[wv] = 1.f / ssum;   // visible after next barrier
  }

  // ---- P write (unnormalized exp) + PV per half; acc accumulates across halves ----
  // Swizzle: flat = (row*1024 + col) ^ (8*(row&7)) — bijective (rows 2048B-aligned).
  f32x4 acc0 = {}, acc1 = {};
  int swz_w = (wv & 7) << 3;
  int swz_r = (l15 & 7) << 3;
#pragma unroll
  for (int hhalf = 0; hhalf < 2; ++hhalf) {
#pragma unroll
    for (int j = 0; j < 16; ++j) {
      int idx = (wv * PSTH + j * 64 + lane) ^ swz_w;
      P[idx] = f2bf1(v[hhalf * 16 + j]);
    }
    __syncthreads();  // half-P complete
    {
      const unsigned short* v0p = vb + (size_t)l15 * S_ + hhalf * HCOLS + wv * 64 + lh * 8;
      const unsigned short* v1p = v0p + 16 * S_;
      int lc0 = wv * 64 + lh * 8;
      short8 a0 = *(const short8*)(P + ((l15 * PSTH + lc0) ^ swz_r));
      short8 a1 = *(const short8*)(P + ((l15 * PSTH + lc0 + 32) ^ swz_r));
      short8 b00 = *(const short8*)(v0p);
      short8 b10 = *(const short8*)(v1p);
      short8 b01 = *(const short8*)(v0p + 32);
      short8 b11 = *(const short8*)(v1p + 32);
      acc0 = __builtin_amdgcn_mfma_f32_16x16x32_bf16(a0, b00, acc0, 0, 0, 0);
      acc1 = __builtin_amdgcn_mfma_f32_16x16x32_bf16(a0, b10, acc1, 0, 0, 0);
      acc0 = __builtin_amdgcn_mfma_f32_16x16x32_bf16(a1, b01, acc0, 0, 0, 0);
      acc1 = __builtin_amdgcn_mfma_f32_16x16x32_bf16(a1, b11, acc1, 0, 0, 0);
    }
    __syncthreads();  // PV reads done; buffer reusable
  }

  // ---- cross-wave reduction of 16 partial out(16x32) tiles ----
#pragma unroll
  for (int r = 0; r < 4; ++r) {
    red[wv * 529 + (lh * 4 + r) * 33 + l15] = acc0[r];
    red[wv * 529 + (lh * 4 + r) * 33 + 16 + l15] = acc1[r];
  }
  __syncthreads();
  if (tid < 512) {
    int row = tid >> 5, d = tid & 31;
    float s = 0.f;
#pragma unroll
    for (int w = 0; w < 16; ++w) s += red[w * 529 + row * 33 + d];
    s *= is_arr[row];
    ao[((size_t)bh * S_ + q0 + row) * 32 + d] = f2bf1(s);
  }
}

// ---------------- K4: output projection ----------------
__global__ __launch_bounds__(256) void k_proj(const unsigned short* __restrict__ wbf,
                                              const unsigned short* __restrict__ ao,
                                              float* __restrict__ out) {
  int b = blockIdx.z;
  int m0 = blockIdx.y * 64, n0 = blockIdx.x * 64;
  int tid = threadIdx.x, lane = tid & 63, wid = tid >> 6;
  int l15 = lane & 15, lh = lane >> 4;
  int wm = (wid >> 1) * 32, wn = (wid & 1) * 32;
  const unsigned short* aob = ao + (size_t)b * H_ * S_ * 32;
  f32x4 acc[2][2] = {};
  int mA = m0 + wm + l15;
  int nB = n0 + wn + l15;
  for (int k0 = 0; k0 < C_; k0 += 32) {
    int kk = k0 + lh * 8;
    int hh = kk >> 5;
    int dd = kk & 31;
    short8 a0 = *(const short8*)(wbf + (size_t)mA * C_ + kk);
    short8 a1 = *(const short8*)(wbf + (size_t)(mA + 16) * C_ + kk);
    short8 b0 = *(const short8*)(aob + ((size_t)hh * S_ + nB) * 32 + dd);
    short8 b1 = *(const short8*)(aob + ((size_t)hh * S_ + nB + 16) * 32 + dd);
    acc[0][0] = __builtin_amdgcn_mfma_f32_16x16x32_bf16(a0, b0, acc[0][0], 0, 0, 0);
    acc[0][1] = __builtin_amdgcn_mfma_f32_16x16x32_bf16(a0, b1, acc[0][1], 0, 0, 0);
    acc[1][0] = __builtin_amdgcn_mfma_f32_16x16x32_bf16(a1, b0, acc[1][0], 0, 0, 0);
    acc[1][1] = __builtin_amdgcn_mfma_f32_16x16x32_bf16(a1, b1, acc[1][1], 0, 0, 0);
  }
  float* ob = out + (size_t)b * C_ * S_;
#pragma unroll
  for (int i = 0; i < 2; ++i)
#pragma unroll
    for (int j = 0; j < 2; ++j)
#pragma unroll
      for (int r = 0; r < 4; ++r) {
        int row = m0 + wm + i * 16 + lh * 4 + r;
        int col = n0 + wn + j * 16 + l15;
        ob[(size_t)row * S_ + col] = acc[i][j][r];
      }
}

extern "C" void kernel_launch(void* const* d_in, const int* in_sizes, int n_in,
                              void* d_out, int out_size, void* d_ws, size_t ws_size,
                              hipStream_t stream) {
  const float* x = (const float*)d_in[0];
  const float* wqkv = (const float*)d_in[1];
  const float* wdw = (const float*)d_in[2];
  const float* wproj = (const float*)d_in[3];
  const float* temp = (const float*)d_in[4];
  float* out = (float*)d_out;

  char* ws = (char*)d_ws;
  size_t off = 0;
  auto alloc = [&](size_t bytes) -> void* {
    void* p = ws + off;
    off += (bytes + 255) & ~(size_t)255;
    return p;
  };
  unsigned short* x_hi     = (unsigned short*)alloc((size_t)B_ * S_ * C_ * 2);
  unsigned short* x_lo     = (unsigned short*)alloc((size_t)B_ * S_ * C_ * 2);
  unsigned short* wq_hi    = (unsigned short*)alloc((size_t)O3_ * C_ * 2);
  unsigned short* wq_lo    = (unsigned short*)alloc((size_t)O3_ * C_ * 2);
  unsigned short* wproj_bf = (unsigned short*)alloc((size_t)C_ * C_ * 2);
  float*          raw      = (float*)alloc((size_t)B_ * O3_ * S_ * 4);
  unsigned short* k_hi     = (unsigned short*)alloc((size_t)B_ * H_ * S_ * 32 * 2);
  unsigned short* k_lo     = (unsigned short*)alloc((size_t)B_ * H_ * S_ * 32 * 2);
  unsigned short* vt       = (unsigned short*)alloc((size_t)B_ * H_ * 32 * S_ * 2);
  unsigned short* q_hi     = x_hi;                 // alias (x dead after k_qkv)
  unsigned short* q_lo     = x_lo;                 // alias
  unsigned short* ao       = (unsigned short*)raw; // alias (raw dead after k_dwnorm)

  (void)hipFuncSetAttribute(reinterpret_cast<const void*>(k_attn),
                            hipFuncAttributeMaxDynamicSharedMemorySize, (int)K3_LDS_BYTES);

  k_convw<<<dim3((O3_ * C_ + 255) / 256), dim3(256), 0, stream>>>(wqkv, wproj, wq_hi, wq_lo, wproj_bf);
  k_xt<<<dim3(S_ / 32, C_ / 32, B_), dim3(32, 8), 0, stream>>>(x, x_hi, x_lo);
  k_qkv<<<dim3(S_ / 64, O3_ / 64, B_), dim3(256), 0, stream>>>(wq_hi, wq_lo, x_hi, x_lo, raw);
  k_dwnorm<<<dim3(S_ / 32, H_, B_), dim3(256), 0, stream>>>(raw, wdw, temp, q_hi, q_lo, k_hi, k_lo, vt);
  k_attn<<<dim3(B_ * H_ * (S_ / QT)), dim3(1024), K3_LDS_BYTES, stream>>>(q_hi, q_lo, k_hi, k_lo, vt, ao);
  k_proj<<<dim3(S_ / 64, C_ / 64, B_), dim3(256), 0, stream>>>(wproj_bf, ao, out);
}